// Round 1
// baseline (1211.704 us; speedup 1.0000x reference)
//
#include <hip/hip_runtime.h>
#include <cstdint>
#include <cstddef>

#define NN   50000
#define EE   800000
#define ET_  (EE + NN)      // 850000 edges incl. self-loops
#define FIN  500
#define HID_ 160
#define NC_  20
#define GG   8

static __device__ __forceinline__ int lbound_i(const int* arr, int n, int val) {
    int lo = 0, hi = n;
    while (lo < hi) { int mid = (lo + hi) >> 1; if (arr[mid] < val) lo = mid + 1; else hi = mid; }
    return lo;
}

// ---------------- CSR build ----------------
__global__ __launch_bounds__(256) void k_hist(const int* __restrict__ ei, int* __restrict__ deg) {
    int e = blockIdx.x * 256 + threadIdx.x;
    if (e >= ET_) return;
    int d = (e < EE) ? ei[EE + e] : (e - EE);
    atomicAdd(&deg[d], 1);
}

__global__ __launch_bounds__(256) void k_scan1(const int* __restrict__ deg, int* __restrict__ rowptr,
                                               int* __restrict__ bsum) {
    __shared__ int s[256];
    int t = threadIdx.x;
    int base = blockIdx.x * 1024 + t * 4;
    int v0 = (base + 0 < NN) ? deg[base + 0] : 0;
    int v1 = (base + 1 < NN) ? deg[base + 1] : 0;
    int v2 = (base + 2 < NN) ? deg[base + 2] : 0;
    int v3 = (base + 3 < NN) ? deg[base + 3] : 0;
    int tot = v0 + v1 + v2 + v3;
    s[t] = tot;
    __syncthreads();
    for (int off = 1; off < 256; off <<= 1) {
        int y = (t >= off) ? s[t - off] : 0;
        __syncthreads();
        s[t] += y;
        __syncthreads();
    }
    int excl = s[t] - tot;
    if (t == 255) bsum[blockIdx.x] = s[255];
    if (base + 0 < NN) rowptr[base + 0] = excl;  excl += v0;
    if (base + 1 < NN) rowptr[base + 1] = excl;  excl += v1;
    if (base + 2 < NN) rowptr[base + 2] = excl;  excl += v2;
    if (base + 3 < NN) rowptr[base + 3] = excl;
}

__global__ void k_scan2(int* __restrict__ bsum, int nb) {
    int t = threadIdx.x; // single wave of 64; nb <= 64
    int v = (t < nb) ? bsum[t] : 0;
    int orig = v;
    for (int off = 1; off < 64; off <<= 1) {
        int y = __shfl_up(v, off);
        if (t >= off) v += y;
    }
    if (t < nb) bsum[t] = v - orig; // exclusive prefix
}

__global__ __launch_bounds__(256) void k_scan3(int* __restrict__ rowptr, const int* __restrict__ bsum,
                                               int* __restrict__ cursor) {
    int i = blockIdx.x * 256 + threadIdx.x;
    if (i < NN) {
        int r = rowptr[i] + bsum[i >> 10];
        rowptr[i] = r;
        cursor[i] = r;
    }
    if (i == NN) rowptr[NN] = ET_;
}

__global__ __launch_bounds__(256) void k_scatter(const int* __restrict__ ei, int* __restrict__ cursor,
                                                 int* __restrict__ eid_s, int* __restrict__ esrc_s) {
    int e = blockIdx.x * 256 + threadIdx.x;
    if (e >= ET_) return;
    int s, d;
    if (e < EE) { s = ei[e]; d = ei[EE + e]; } else { s = e - EE; d = e - EE; }
    int slot = atomicAdd(&cursor[d], 1);
    eid_s[slot]  = e;
    esrc_s[slot] = s;
}

// ---------------- GEMM: C[M,160] = A[M,K] @ B[K,160] (+bias, +leaky) ----------------
__global__ __launch_bounds__(256) void k_gemm160(const float* __restrict__ A, const float* __restrict__ B,
                                                 float* __restrict__ C, int M, int K,
                                                 const float* __restrict__ bias, int act) {
    const int BM = 64, BK = 20;
    __shared__ float As[BM * BK];
    __shared__ float Bs[BK * HID_];
    int tid = threadIdx.x;
    int tx = tid & 15, ty = tid >> 4;
    int row0 = blockIdx.x * BM;
    float acc[4][10];
#pragma unroll
    for (int i = 0; i < 4; i++)
#pragma unroll
        for (int j = 0; j < 10; j++) acc[i][j] = 0.f;

    for (int k0 = 0; k0 < K; k0 += BK) {
        for (int idx = tid; idx < BM * BK; idx += 256) {
            int r = idx / BK, c = idx - r * BK;
            int gr = row0 + r, gc = k0 + c;
            As[idx] = (gr < M && gc < K) ? A[(size_t)gr * K + gc] : 0.f;
        }
        for (int idx = tid; idx < BK * HID_; idx += 256) {
            int r = idx / HID_, c = idx - r * HID_;
            int gk = k0 + r;
            Bs[idx] = (gk < K) ? B[(size_t)gk * HID_ + c] : 0.f;
        }
        __syncthreads();
#pragma unroll
        for (int k = 0; k < BK; k++) {
            float av[4], bv[10];
#pragma unroll
            for (int i = 0; i < 4; i++) av[i] = As[(ty * 4 + i) * BK + k];
#pragma unroll
            for (int j = 0; j < 10; j++) bv[j] = Bs[k * HID_ + tx * 10 + j];
#pragma unroll
            for (int i = 0; i < 4; i++)
#pragma unroll
                for (int j = 0; j < 10; j++) acc[i][j] += av[i] * bv[j];
        }
        __syncthreads();
    }
#pragma unroll
    for (int i = 0; i < 4; i++) {
        int gr = row0 + ty * 4 + i;
        if (gr >= M) continue;
        size_t ob = (size_t)gr * HID_ + tx * 10;
#pragma unroll
        for (int j = 0; j < 10; j++) {
            float v = acc[i][j];
            if (bias) v += bias[tx * 10 + j];
            if (act)  v = v > 0.f ? v : 0.01f * v;
            C[ob + j] = v;
        }
    }
}

// ---------------- per-node attention coefficients ----------------
__global__ __launch_bounds__(256) void k_node_att(const float* __restrict__ hmat,
                                                  const float* __restrict__ asrc, const float* __restrict__ adst,
                                                  float* __restrict__ als, float* __restrict__ ald) {
    int node = blockIdx.x * 4 + (threadIdx.x >> 6);
    int lane = threadIdx.x & 63;
    if (node >= NN) return;
    const float* row = &hmat[(size_t)node * HID_];
    float v0 = row[lane], v1 = row[lane + 64];
    float s0 = v0 * asrc[lane],      d0 = v0 * adst[lane];
    float s1 = v1 * asrc[lane + 64], d1 = v1 * adst[lane + 64];
    float s2 = 0.f, d2 = 0.f;
    if (lane < 32) {
        float v2 = row[lane + 128];
        s2 = v2 * asrc[lane + 128];
        d2 = v2 * adst[lane + 128];
    }
#pragma unroll
    for (int off = 16; off >= 1; off >>= 1) {
        s0 += __shfl_xor(s0, off); s1 += __shfl_xor(s1, off); s2 += __shfl_xor(s2, off);
        d0 += __shfl_xor(d0, off); d1 += __shfl_xor(d1, off); d2 += __shfl_xor(d2, off);
    }
    if (lane == 0) {
        als[node * 5 + 0] = s0; als[node * 5 + 2] = s1; als[node * 5 + 4] = s2;
        ald[node * 5 + 0] = d0; ald[node * 5 + 2] = d1; ald[node * 5 + 4] = d2;
    }
    if (lane == 32) {
        als[node * 5 + 1] = s0; als[node * 5 + 3] = s1;
        ald[node * 5 + 1] = d0; ald[node * 5 + 3] = d1;
    }
}

// ---------------- edge softmax (wave per destination node) ----------------
__global__ __launch_bounds__(256) void k_edge_softmax(const int* __restrict__ rowptr,
                                                      const int* __restrict__ eid_s, const int* __restrict__ esrc_s,
                                                      const float* __restrict__ als, const float* __restrict__ ald,
                                                      float* __restrict__ alpha) {
    int node = blockIdx.x * 4 + (threadIdx.x >> 6);
    int lane = threadIdx.x & 63;
    if (node >= NN) return;
    int start = rowptr[node], end = rowptr[node + 1];
    float ad[5];
#pragma unroll
    for (int h = 0; h < 5; h++) ad[h] = ald[node * 5 + h];
    float mx[5];
#pragma unroll
    for (int h = 0; h < 5; h++) mx[h] = -1e30f;
    for (int j = start + lane; j < end; j += 64) {
        int src = esrc_s[j];
        int e   = eid_s[j];
        const float* as = &als[(size_t)src * 5];
        float* ap = &alpha[(size_t)e * 5];
#pragma unroll
        for (int h = 0; h < 5; h++) {
            float l = as[h] + ad[h];
            l = l > 0.f ? l : 0.2f * l;
            ap[h] = l;
            mx[h] = fmaxf(mx[h], l);
        }
    }
#pragma unroll
    for (int off = 32; off >= 1; off >>= 1)
#pragma unroll
        for (int h = 0; h < 5; h++) mx[h] = fmaxf(mx[h], __shfl_xor(mx[h], off));
    float sm[5] = {0.f, 0.f, 0.f, 0.f, 0.f};
    for (int j = start + lane; j < end; j += 64) {
        int e = eid_s[j];
        float* ap = &alpha[(size_t)e * 5];
#pragma unroll
        for (int h = 0; h < 5; h++) {
            float ex = __expf(ap[h] - mx[h]);
            ap[h] = ex;
            sm[h] += ex;
        }
    }
#pragma unroll
    for (int off = 32; off >= 1; off >>= 1)
#pragma unroll
        for (int h = 0; h < 5; h++) sm[h] += __shfl_xor(sm[h], off);
    float inv[5];
#pragma unroll
    for (int h = 0; h < 5; h++) inv[h] = 1.f / (sm[h] + 1e-16f);
    for (int j = start + lane; j < end; j += 64) {
        int e = eid_s[j];
        float* ap = &alpha[(size_t)e * 5];
#pragma unroll
        for (int h = 0; h < 5; h++) ap[h] *= inv[h];
    }
}

// ---------------- aggregation + bias + leaky(0.01) + LayerNorm (wave per node) ----------------
__global__ __launch_bounds__(256) void k_agg_ln(const int* __restrict__ rowptr,
                                                const int* __restrict__ eid_s, const int* __restrict__ esrc_s,
                                                const float* __restrict__ hmat, const float* __restrict__ alpha,
                                                const float* __restrict__ bias,
                                                const float* __restrict__ lns, const float* __restrict__ lnb,
                                                float* __restrict__ out) {
    int node = blockIdx.x * 4 + (threadIdx.x >> 6);
    int lane = threadIdx.x & 63;
    if (node >= NN) return;
    int start = rowptr[node], end = rowptr[node + 1];
    int h0 = lane >> 5;      // head of channel `lane` (0 or 1)
    int h1 = h0 + 2;         // head of channel lane+64 (2 or 3)
    bool lo32 = lane < 32;
    float a0 = 0.f, a1 = 0.f, a2 = 0.f;
    for (int j = start; j < end; j++) {
        int src = esrc_s[j];
        int e   = eid_s[j];
        const float* ap  = &alpha[(size_t)e * 5];
        const float* row = &hmat[(size_t)src * HID_];
        a0 += ap[h0] * row[lane];
        a1 += ap[h1] * row[lane + 64];
        if (lo32) a2 += ap[4] * row[lane + 128];
    }
    float v0 = a0 + bias[lane];       v0 = v0 > 0.f ? v0 : 0.01f * v0;
    float v1 = a1 + bias[lane + 64];  v1 = v1 > 0.f ? v1 : 0.01f * v1;
    float v2 = 0.f;
    if (lo32) { v2 = a2 + bias[lane + 128]; v2 = v2 > 0.f ? v2 : 0.01f * v2; }
    float s  = v0 + v1 + v2;
    float sq = v0 * v0 + v1 * v1 + v2 * v2;
#pragma unroll
    for (int off = 32; off >= 1; off >>= 1) {
        s  += __shfl_xor(s, off);
        sq += __shfl_xor(sq, off);
    }
    float m = s * (1.f / 160.f);
    float r = rsqrtf(sq * (1.f / 160.f) - m * m + 1e-5f);
    size_t ob = (size_t)node * HID_;
    out[ob + lane]       = (v0 - m) * r * lns[lane]       + lnb[lane];
    out[ob + lane + 64]  = (v1 - m) * r * lns[lane + 64]  + lnb[lane + 64];
    if (lo32)
        out[ob + lane + 128] = (v2 - m) * r * lns[lane + 128] + lnb[lane + 128];
}

// ---------------- global mean pool (partial sums, atomic into pooled) ----------------
__global__ __launch_bounds__(192) void k_pool(const float* __restrict__ xo, const int* __restrict__ batch,
                                              float* __restrict__ pooled) {
    int g = blockIdx.x, chunk = blockIdx.y;
    int lo = lbound_i(batch, NN, g), hi = lbound_i(batch, NN, g + 1);
    int len = hi - lo;
    if (len <= 0) return;
    int per = (len + 31) / 32;
    int s = lo + chunk * per;
    int e = min(s + per, hi);
    if (s >= e) return;
    int ch = threadIdx.x;
    if (ch >= HID_) return;
    float acc = 0.f;
    for (int n = s; n < e; n++) acc += xo[(size_t)n * HID_ + ch];
    atomicAdd(&pooled[g * HID_ + ch], acc);
}

// ---------------- readout MLP (single block) ----------------
__global__ __launch_bounds__(256) void k_mlp(const float* __restrict__ pooled, const int* __restrict__ batch,
                                             const float* __restrict__ W1, const float* __restrict__ b1,
                                             const float* __restrict__ lns, const float* __restrict__ lnb,
                                             const float* __restrict__ W2, const float* __restrict__ b2,
                                             float* __restrict__ rec) {
    __shared__ float P[GG][HID_];
    __shared__ float Z[GG][HID_];
    __shared__ float mu[GG], rr[GG], ic[GG];
    int t = threadIdx.x;
    if (t < GG) {
        int lo = lbound_i(batch, NN, t), hi = lbound_i(batch, NN, t + 1);
        ic[t] = 1.f / fmaxf((float)(hi - lo), 1.f);
    }
    __syncthreads();
    for (int i = t; i < GG * HID_; i += 256) P[i / HID_][i % HID_] = pooled[i] * ic[i / HID_];
    __syncthreads();
    for (int i = t; i < GG * HID_; i += 256) {
        int g = i / HID_, j = i % HID_;
        float acc = b1[j];
        for (int k = 0; k < HID_; k++) acc += P[g][k] * W1[k * HID_ + j];
        Z[g][j] = acc;
    }
    __syncthreads();
    if (t < GG) {
        float s = 0.f, sq = 0.f;
        for (int k = 0; k < HID_; k++) { float z = Z[t][k]; s += z; sq += z * z; }
        float m = s / (float)HID_;
        mu[t] = m;
        rr[t] = rsqrtf(sq / (float)HID_ - m * m + 1e-5f);
    }
    __syncthreads();
    for (int i = t; i < GG * HID_; i += 256) {
        int g = i / HID_, j = i % HID_;
        float z = (Z[g][j] - mu[g]) * rr[g] * lns[j] + lnb[j];
        Z[g][j] = fmaxf(z, 0.f);
    }
    __syncthreads();
    for (int i = t; i < GG * NC_; i += 256) {
        int g = i / NC_, j = i % NC_;
        float acc = b2[j];
        for (int k = 0; k < HID_; k++) acc += Z[g][k] * W2[k * NC_ + j];
        rec[g * NC_ + j] = acc;
    }
}

extern "C" void kernel_launch(void* const* d_in, const int* in_sizes, int n_in,
                              void* d_out, int out_size, void* d_ws, size_t ws_size,
                              hipStream_t stream) {
    const float* x    = (const float*)d_in[0];
    const int*   ei   = (const int*)d_in[1];
    const int*   batch= (const int*)d_in[2];
    const float* W1   = (const float*)d_in[3];
    const float* as1  = (const float*)d_in[4];
    const float* ad1  = (const float*)d_in[5];
    const float* b1   = (const float*)d_in[6];
    const float* ln1s = (const float*)d_in[7];
    const float* ln1b = (const float*)d_in[8];
    const float* W2   = (const float*)d_in[9];
    const float* as2  = (const float*)d_in[10];
    const float* ad2  = (const float*)d_in[11];
    const float* b2   = (const float*)d_in[12];
    const float* ln2s = (const float*)d_in[13];
    const float* ln2b = (const float*)d_in[14];
    const float* Wm   = (const float*)d_in[15];
    const float* bm   = (const float*)d_in[16];
    const float* Wm1  = (const float*)d_in[17];
    const float* bm1  = (const float*)d_in[18];
    const float* ln3s = (const float*)d_in[19];
    const float* ln3b = (const float*)d_in[20];
    const float* Wm2  = (const float*)d_in[21];
    const float* bm2  = (const float*)d_in[22];

    float* out    = (float*)d_out;
    float* xo     = out;                              // N*160
    float* rec    = out + (size_t)NN * HID_;          // 8*20
    float* alpha1 = rec + GG * NC_;                   // ET*5
    float* alpha2 = alpha1 + (size_t)ET_ * 5;         // ET*5

    char* w = (char*)d_ws;
    auto carve = [&](size_t bytes) { char* p = w; w += (bytes + 255) & ~(size_t)255; return p; };
    int*   deg    = (int*)carve((size_t)NN * 4);
    int*   rowptr = (int*)carve((size_t)(NN + 1) * 4);
    int*   cursor = (int*)carve((size_t)NN * 4);
    int*   eid_s  = (int*)carve((size_t)ET_ * 4);
    int*   esrc_s = (int*)carve((size_t)ET_ * 4);
    int*   bsum   = (int*)carve(64 * 4);
    float* hbuf   = (float*)carve((size_t)NN * HID_ * 4);
    float* xbuf   = (float*)carve((size_t)NN * HID_ * 4);
    float* als    = (float*)carve((size_t)NN * 5 * 4);
    float* ald    = (float*)carve((size_t)NN * 5 * 4);
    float* pooled = (float*)carve((size_t)GG * HID_ * 4);

    // ---- CSR by destination (rebuilt every call; ws is re-poisoned) ----
    hipMemsetAsync(deg, 0, (size_t)NN * 4, stream);
    k_hist<<<(ET_ + 255) / 256, 256, 0, stream>>>(ei, deg);
    int nb = (NN + 1023) / 1024;
    k_scan1<<<nb, 256, 0, stream>>>(deg, rowptr, bsum);
    k_scan2<<<1, 64, 0, stream>>>(bsum, nb);
    k_scan3<<<(NN + 1 + 255) / 256, 256, 0, stream>>>(rowptr, bsum, cursor);
    k_scatter<<<(ET_ + 255) / 256, 256, 0, stream>>>(ei, cursor, eid_s, esrc_s);

    const int NWB = (NN + 3) / 4;       // wave-per-node blocks (4 waves/block)
    const int GB  = (NN + 63) / 64;     // GEMM blocks

    // ---- layer 1 ----
    k_gemm160<<<GB, 256, 0, stream>>>(x, W1, hbuf, NN, FIN, nullptr, 0);
    k_node_att<<<NWB, 256, 0, stream>>>(hbuf, as1, ad1, als, ald);
    k_edge_softmax<<<NWB, 256, 0, stream>>>(rowptr, eid_s, esrc_s, als, ald, alpha1);
    k_agg_ln<<<NWB, 256, 0, stream>>>(rowptr, eid_s, esrc_s, hbuf, alpha1, b1, ln1s, ln1b, xbuf);

    // ---- layer 2 ----
    k_gemm160<<<GB, 256, 0, stream>>>(xbuf, W2, hbuf, NN, HID_, nullptr, 0);
    k_node_att<<<NWB, 256, 0, stream>>>(hbuf, as2, ad2, als, ald);
    k_edge_softmax<<<NWB, 256, 0, stream>>>(rowptr, eid_s, esrc_s, als, ald, alpha2);
    k_agg_ln<<<NWB, 256, 0, stream>>>(rowptr, eid_s, esrc_s, hbuf, alpha2, b2, ln2s, ln2b, xbuf);

    // ---- readout ----
    k_gemm160<<<GB, 256, 0, stream>>>(xbuf, Wm, xo, NN, HID_, bm, 1);
    hipMemsetAsync(pooled, 0, (size_t)GG * HID_ * 4, stream);
    k_pool<<<dim3(GG, 32), 192, 0, stream>>>(xo, batch, pooled);
    k_mlp<<<1, 256, 0, stream>>>(pooled, batch, Wm1, bm1, ln3s, ln3b, Wm2, bm2, rec);
}

// Round 2
// 1054.465 us; speedup vs baseline: 1.1491x; 1.1491x over previous
//
#include <hip/hip_runtime.h>
#include <hip/hip_bf16.h>
#include <cstdint>
#include <cstddef>

#define NN   50000
#define EE   800000
#define ET_  (EE + NN)      // 850000 edges incl. self-loops
#define FIN  500
#define HID_ 160
#define NC_  20
#define GG   8

static __device__ __forceinline__ int lbound_i(const int* arr, int n, int val) {
    int lo = 0, hi = n;
    while (lo < hi) { int mid = (lo + hi) >> 1; if (arr[mid] < val) lo = mid + 1; else hi = mid; }
    return lo;
}

// ---------------- CSR build ----------------
__global__ __launch_bounds__(256) void k_hist(const int* __restrict__ ei, int* __restrict__ deg) {
    int e = blockIdx.x * 256 + threadIdx.x;
    if (e >= ET_) return;
    int d = (e < EE) ? ei[EE + e] : (e - EE);
    atomicAdd(&deg[d], 1);
}

__global__ __launch_bounds__(256) void k_scan1(const int* __restrict__ deg, int* __restrict__ rowptr,
                                               int* __restrict__ bsum) {
    __shared__ int s[256];
    int t = threadIdx.x;
    int base = blockIdx.x * 1024 + t * 4;
    int v0 = (base + 0 < NN) ? deg[base + 0] : 0;
    int v1 = (base + 1 < NN) ? deg[base + 1] : 0;
    int v2 = (base + 2 < NN) ? deg[base + 2] : 0;
    int v3 = (base + 3 < NN) ? deg[base + 3] : 0;
    int tot = v0 + v1 + v2 + v3;
    s[t] = tot;
    __syncthreads();
    for (int off = 1; off < 256; off <<= 1) {
        int y = (t >= off) ? s[t - off] : 0;
        __syncthreads();
        s[t] += y;
        __syncthreads();
    }
    int excl = s[t] - tot;
    if (t == 255) bsum[blockIdx.x] = s[255];
    if (base + 0 < NN) rowptr[base + 0] = excl;  excl += v0;
    if (base + 1 < NN) rowptr[base + 1] = excl;  excl += v1;
    if (base + 2 < NN) rowptr[base + 2] = excl;  excl += v2;
    if (base + 3 < NN) rowptr[base + 3] = excl;
}

__global__ void k_scan2(int* __restrict__ bsum, int nb) {
    int t = threadIdx.x; // single wave of 64; nb <= 64
    int v = (t < nb) ? bsum[t] : 0;
    int orig = v;
    for (int off = 1; off < 64; off <<= 1) {
        int y = __shfl_up(v, off);
        if (t >= off) v += y;
    }
    if (t < nb) bsum[t] = v - orig; // exclusive prefix
}

__global__ __launch_bounds__(256) void k_scan3(int* __restrict__ rowptr, const int* __restrict__ bsum,
                                               int* __restrict__ cursor) {
    int i = blockIdx.x * 256 + threadIdx.x;
    if (i < NN) {
        int r = rowptr[i] + bsum[i >> 10];
        rowptr[i] = r;
        cursor[i] = r;
    }
    if (i == NN) rowptr[NN] = ET_;
}

__global__ __launch_bounds__(256) void k_scatter(const int* __restrict__ ei, int* __restrict__ cursor,
                                                 int* __restrict__ eid_s, int* __restrict__ esrc_s) {
    int e = blockIdx.x * 256 + threadIdx.x;
    if (e >= ET_) return;
    int s, d;
    if (e < EE) { s = ei[e]; d = ei[EE + e]; } else { s = e - EE; d = e - EE; }
    int slot = atomicAdd(&cursor[d], 1);
    eid_s[slot]  = e;
    esrc_s[slot] = s;
}

// ---------------- GEMM: C[M,160] = A[M,K] @ B[K,160] (+bias, +leaky), fp32/bf16 out ----
// BM=64, BK=16, full N=160. As padded to [64][20] (20-float row stride: 16B-aligned
// float4 reads, 2-way-max bank aliasing which is free). B tile is a contiguous slab.
__global__ __launch_bounds__(256) void k_gemm160v(const float* __restrict__ A, const float* __restrict__ B,
                                                  float* __restrict__ C, __hip_bfloat16* __restrict__ Cb,
                                                  int M, int K,
                                                  const float* __restrict__ bias, int act) {
    __shared__ float As[64][20];
    __shared__ float Bs[16][160];
    int tid = threadIdx.x;
    int tx = tid & 15, ty = tid >> 4;
    int row0 = blockIdx.x * 64;
    int arow = tid >> 2;            // 0..63
    int acol = (tid & 3) * 4;       // 0,4,8,12
    float acc[4][10];
#pragma unroll
    for (int i = 0; i < 4; i++)
#pragma unroll
        for (int j = 0; j < 10; j++) acc[i][j] = 0.f;

    const float4 z4 = make_float4(0.f, 0.f, 0.f, 0.f);
    for (int k0 = 0; k0 < K; k0 += 16) {
        // A tile: one float4 per thread (K is a multiple of 4 for both 500 and 160)
        {
            int gr = row0 + arow;
            float4 v = z4;
            if (gr < M && (k0 + acol) < K)
                v = *reinterpret_cast<const float4*>(&A[(size_t)gr * K + k0 + acol]);
            *reinterpret_cast<float4*>(&As[arow][acol]) = v;
        }
        // B tile: contiguous slab of 16*160 floats = 640 float4
        {
            const float4* Bg = reinterpret_cast<const float4*>(B + (size_t)k0 * HID_);
            float4* Bs4 = reinterpret_cast<float4*>(&Bs[0][0]);
            for (int idx = tid; idx < 640; idx += 256) {
                int krow = idx / 40;
                Bs4[idx] = (k0 + krow < K) ? Bg[idx] : z4;
            }
        }
        __syncthreads();
#pragma unroll
        for (int k4 = 0; k4 < 4; k4++) {
            float4 a[4];
#pragma unroll
            for (int i = 0; i < 4; i++)
                a[i] = *reinterpret_cast<const float4*>(&As[ty * 4 + i][k4 * 4]);
            const float ax[4][4] = {
                {a[0].x, a[0].y, a[0].z, a[0].w},
                {a[1].x, a[1].y, a[1].z, a[1].w},
                {a[2].x, a[2].y, a[2].z, a[2].w},
                {a[3].x, a[3].y, a[3].z, a[3].w}};
#pragma unroll
            for (int kk = 0; kk < 4; kk++) {
                float bv[10];
#pragma unroll
                for (int j = 0; j < 10; j++) bv[j] = Bs[k4 * 4 + kk][tx * 10 + j];
#pragma unroll
                for (int i = 0; i < 4; i++)
#pragma unroll
                    for (int j = 0; j < 10; j++) acc[i][j] += ax[i][kk] * bv[j];
            }
        }
        __syncthreads();
    }
#pragma unroll
    for (int i = 0; i < 4; i++) {
        int gr = row0 + ty * 4 + i;
        if (gr >= M) continue;
        size_t ob = (size_t)gr * HID_ + tx * 10;
#pragma unroll
        for (int j = 0; j < 10; j++) {
            float v = acc[i][j];
            if (bias) v += bias[tx * 10 + j];
            if (act)  v = v > 0.f ? v : 0.01f * v;
            if (C)  C[ob + j] = v;
            if (Cb) Cb[ob + j] = __float2bfloat16(v);
        }
    }
}

// ---------------- per-node attention coefficients (bf16 h) ----------------
__global__ __launch_bounds__(256) void k_node_att(const __hip_bfloat16* __restrict__ hmat,
                                                  const float* __restrict__ asrc, const float* __restrict__ adst,
                                                  float* __restrict__ als, float* __restrict__ ald) {
    int node = blockIdx.x * 4 + (threadIdx.x >> 6);
    int lane = threadIdx.x & 63;
    if (node >= NN) return;
    const __hip_bfloat16* row = &hmat[(size_t)node * HID_];
    float v0 = __bfloat162float(row[lane]);
    float v1 = __bfloat162float(row[lane + 64]);
    float s0 = v0 * asrc[lane],      d0 = v0 * adst[lane];
    float s1 = v1 * asrc[lane + 64], d1 = v1 * adst[lane + 64];
    float s2 = 0.f, d2 = 0.f;
    if (lane < 32) {
        float v2 = __bfloat162float(row[lane + 128]);
        s2 = v2 * asrc[lane + 128];
        d2 = v2 * adst[lane + 128];
    }
#pragma unroll
    for (int off = 16; off >= 1; off >>= 1) {
        s0 += __shfl_xor(s0, off); s1 += __shfl_xor(s1, off); s2 += __shfl_xor(s2, off);
        d0 += __shfl_xor(d0, off); d1 += __shfl_xor(d1, off); d2 += __shfl_xor(d2, off);
    }
    if (lane == 0) {
        als[node * 5 + 0] = s0; als[node * 5 + 2] = s1; als[node * 5 + 4] = s2;
        ald[node * 5 + 0] = d0; ald[node * 5 + 2] = d1; ald[node * 5 + 4] = d2;
    }
    if (lane == 32) {
        als[node * 5 + 1] = s0; als[node * 5 + 3] = s1;
        ald[node * 5 + 1] = d0; ald[node * 5 + 3] = d1;
    }
}

// ---------------- edge softmax (wave per destination node) ----------------
__global__ __launch_bounds__(256) void k_edge_softmax(const int* __restrict__ rowptr,
                                                      const int* __restrict__ eid_s, const int* __restrict__ esrc_s,
                                                      const float* __restrict__ als, const float* __restrict__ ald,
                                                      float* __restrict__ alpha) {
    int node = blockIdx.x * 4 + (threadIdx.x >> 6);
    int lane = threadIdx.x & 63;
    if (node >= NN) return;
    int start = rowptr[node], end = rowptr[node + 1];
    float ad[5];
#pragma unroll
    for (int h = 0; h < 5; h++) ad[h] = ald[node * 5 + h];
    float mx[5];
#pragma unroll
    for (int h = 0; h < 5; h++) mx[h] = -1e30f;
    for (int j = start + lane; j < end; j += 64) {
        int src = esrc_s[j];
        int e   = eid_s[j];
        const float* as = &als[(size_t)src * 5];
        float* ap = &alpha[(size_t)e * 5];
#pragma unroll
        for (int h = 0; h < 5; h++) {
            float l = as[h] + ad[h];
            l = l > 0.f ? l : 0.2f * l;
            ap[h] = l;
            mx[h] = fmaxf(mx[h], l);
        }
    }
#pragma unroll
    for (int off = 32; off >= 1; off >>= 1)
#pragma unroll
        for (int h = 0; h < 5; h++) mx[h] = fmaxf(mx[h], __shfl_xor(mx[h], off));
    float sm[5] = {0.f, 0.f, 0.f, 0.f, 0.f};
    for (int j = start + lane; j < end; j += 64) {
        int e = eid_s[j];
        float* ap = &alpha[(size_t)e * 5];
#pragma unroll
        for (int h = 0; h < 5; h++) {
            float ex = __expf(ap[h] - mx[h]);
            ap[h] = ex;
            sm[h] += ex;
        }
    }
#pragma unroll
    for (int off = 32; off >= 1; off >>= 1)
#pragma unroll
        for (int h = 0; h < 5; h++) sm[h] += __shfl_xor(sm[h], off);
    float inv[5];
#pragma unroll
    for (int h = 0; h < 5; h++) inv[h] = 1.f / (sm[h] + 1e-16f);
    for (int j = start + lane; j < end; j += 64) {
        int e = eid_s[j];
        float* ap = &alpha[(size_t)e * 5];
#pragma unroll
        for (int h = 0; h < 5; h++) ap[h] *= inv[h];
    }
}

// ---------------- aggregation + bias + leaky(0.01) + LayerNorm (wave per node, bf16 h) ----
__global__ __launch_bounds__(256) void k_agg_ln(const int* __restrict__ rowptr,
                                                const int* __restrict__ eid_s, const int* __restrict__ esrc_s,
                                                const __hip_bfloat16* __restrict__ hmat, const float* __restrict__ alpha,
                                                const float* __restrict__ bias,
                                                const float* __restrict__ lns, const float* __restrict__ lnb,
                                                float* __restrict__ out) {
    int node = blockIdx.x * 4 + (threadIdx.x >> 6);
    int lane = threadIdx.x & 63;
    if (node >= NN) return;
    int start = rowptr[node], end = rowptr[node + 1];
    int h0 = lane >> 5;      // head of channel `lane` (0 or 1)
    int h1 = h0 + 2;         // head of channel lane+64 (2 or 3)
    bool lo32 = lane < 32;
    float a0 = 0.f, a1 = 0.f, a2 = 0.f;
    float c0 = 0.f, c1 = 0.f, c2 = 0.f;
    int j = start;
    for (; j + 1 < end; j += 2) {
        int sA = esrc_s[j], sB = esrc_s[j + 1];
        int eA = eid_s[j],  eB = eid_s[j + 1];
        const float* apA = &alpha[(size_t)eA * 5];
        const float* apB = &alpha[(size_t)eB * 5];
        const __hip_bfloat16* rA = &hmat[(size_t)sA * HID_];
        const __hip_bfloat16* rB = &hmat[(size_t)sB * HID_];
        float wA0 = apA[h0], wA1 = apA[h1];
        float wB0 = apB[h0], wB1 = apB[h1];
        float vA0 = __bfloat162float(rA[lane]);
        float vA1 = __bfloat162float(rA[lane + 64]);
        float vB0 = __bfloat162float(rB[lane]);
        float vB1 = __bfloat162float(rB[lane + 64]);
        a0 += wA0 * vA0; c0 += wB0 * vB0;
        a1 += wA1 * vA1; c1 += wB1 * vB1;
        if (lo32) {
            a2 += apA[4] * __bfloat162float(rA[lane + 128]);
            c2 += apB[4] * __bfloat162float(rB[lane + 128]);
        }
    }
    if (j < end) {
        int src = esrc_s[j];
        int e   = eid_s[j];
        const float* ap  = &alpha[(size_t)e * 5];
        const __hip_bfloat16* row = &hmat[(size_t)src * HID_];
        a0 += ap[h0] * __bfloat162float(row[lane]);
        a1 += ap[h1] * __bfloat162float(row[lane + 64]);
        if (lo32) a2 += ap[4] * __bfloat162float(row[lane + 128]);
    }
    a0 += c0; a1 += c1; a2 += c2;
    float v0 = a0 + bias[lane];       v0 = v0 > 0.f ? v0 : 0.01f * v0;
    float v1 = a1 + bias[lane + 64];  v1 = v1 > 0.f ? v1 : 0.01f * v1;
    float v2 = 0.f;
    if (lo32) { v2 = a2 + bias[lane + 128]; v2 = v2 > 0.f ? v2 : 0.01f * v2; }
    float s  = v0 + v1 + v2;
    float sq = v0 * v0 + v1 * v1 + v2 * v2;
#pragma unroll
    for (int off = 32; off >= 1; off >>= 1) {
        s  += __shfl_xor(s, off);
        sq += __shfl_xor(sq, off);
    }
    float m = s * (1.f / 160.f);
    float r = rsqrtf(sq * (1.f / 160.f) - m * m + 1e-5f);
    size_t ob = (size_t)node * HID_;
    out[ob + lane]       = (v0 - m) * r * lns[lane]       + lnb[lane];
    out[ob + lane + 64]  = (v1 - m) * r * lns[lane + 64]  + lnb[lane + 64];
    if (lo32)
        out[ob + lane + 128] = (v2 - m) * r * lns[lane + 128] + lnb[lane + 128];
}

// ---------------- global mean pool (partial sums, atomic into pooled) ----------------
__global__ __launch_bounds__(192) void k_pool(const float* __restrict__ xo, const int* __restrict__ batch,
                                              float* __restrict__ pooled) {
    int g = blockIdx.x, chunk = blockIdx.y;
    int lo = lbound_i(batch, NN, g), hi = lbound_i(batch, NN, g + 1);
    int len = hi - lo;
    if (len <= 0) return;
    int per = (len + 31) / 32;
    int s = lo + chunk * per;
    int e = min(s + per, hi);
    if (s >= e) return;
    int ch = threadIdx.x;
    if (ch >= HID_) return;
    float acc = 0.f;
    for (int n = s; n < e; n++) acc += xo[(size_t)n * HID_ + ch];
    atomicAdd(&pooled[g * HID_ + ch], acc);
}

// ---------------- readout MLP (single block) ----------------
__global__ __launch_bounds__(256) void k_mlp(const float* __restrict__ pooled, const int* __restrict__ batch,
                                             const float* __restrict__ W1, const float* __restrict__ b1,
                                             const float* __restrict__ lns, const float* __restrict__ lnb,
                                             const float* __restrict__ W2, const float* __restrict__ b2,
                                             float* __restrict__ rec) {
    __shared__ float P[GG][HID_];
    __shared__ float Z[GG][HID_];
    __shared__ float mu[GG], rr[GG], ic[GG];
    int t = threadIdx.x;
    if (t < GG) {
        int lo = lbound_i(batch, NN, t), hi = lbound_i(batch, NN, t + 1);
        ic[t] = 1.f / fmaxf((float)(hi - lo), 1.f);
    }
    __syncthreads();
    for (int i = t; i < GG * HID_; i += 256) P[i / HID_][i % HID_] = pooled[i] * ic[i / HID_];
    __syncthreads();
    for (int i = t; i < GG * HID_; i += 256) {
        int g = i / HID_, j = i % HID_;
        float acc = b1[j];
        for (int k = 0; k < HID_; k++) acc += P[g][k] * W1[k * HID_ + j];
        Z[g][j] = acc;
    }
    __syncthreads();
    if (t < GG) {
        float s = 0.f, sq = 0.f;
        for (int k = 0; k < HID_; k++) { float z = Z[t][k]; s += z; sq += z * z; }
        float m = s / (float)HID_;
        mu[t] = m;
        rr[t] = rsqrtf(sq / (float)HID_ - m * m + 1e-5f);
    }
    __syncthreads();
    for (int i = t; i < GG * HID_; i += 256) {
        int g = i / HID_, j = i % HID_;
        float z = (Z[g][j] - mu[g]) * rr[g] * lns[j] + lnb[j];
        Z[g][j] = fmaxf(z, 0.f);
    }
    __syncthreads();
    for (int i = t; i < GG * NC_; i += 256) {
        int g = i / NC_, j = i % NC_;
        float acc = b2[j];
        for (int k = 0; k < HID_; k++) acc += Z[g][k] * W2[k * NC_ + j];
        rec[g * NC_ + j] = acc;
    }
}

extern "C" void kernel_launch(void* const* d_in, const int* in_sizes, int n_in,
                              void* d_out, int out_size, void* d_ws, size_t ws_size,
                              hipStream_t stream) {
    const float* x    = (const float*)d_in[0];
    const int*   ei   = (const int*)d_in[1];
    const int*   batch= (const int*)d_in[2];
    const float* W1   = (const float*)d_in[3];
    const float* as1  = (const float*)d_in[4];
    const float* ad1  = (const float*)d_in[5];
    const float* b1   = (const float*)d_in[6];
    const float* ln1s = (const float*)d_in[7];
    const float* ln1b = (const float*)d_in[8];
    const float* W2   = (const float*)d_in[9];
    const float* as2  = (const float*)d_in[10];
    const float* ad2  = (const float*)d_in[11];
    const float* b2   = (const float*)d_in[12];
    const float* ln2s = (const float*)d_in[13];
    const float* ln2b = (const float*)d_in[14];
    const float* Wm   = (const float*)d_in[15];
    const float* bm   = (const float*)d_in[16];
    const float* Wm1  = (const float*)d_in[17];
    const float* bm1  = (const float*)d_in[18];
    const float* ln3s = (const float*)d_in[19];
    const float* ln3b = (const float*)d_in[20];
    const float* Wm2  = (const float*)d_in[21];
    const float* bm2  = (const float*)d_in[22];

    float* out    = (float*)d_out;
    float* xo     = out;                              // N*160
    float* rec    = out + (size_t)NN * HID_;          // 8*20
    float* alpha1 = rec + GG * NC_;                   // ET*5
    float* alpha2 = alpha1 + (size_t)ET_ * 5;         // ET*5

    char* w = (char*)d_ws;
    auto carve = [&](size_t bytes) { char* p = w; w += (bytes + 255) & ~(size_t)255; return p; };
    int*   deg    = (int*)carve((size_t)NN * 4);
    int*   rowptr = (int*)carve((size_t)(NN + 1) * 4);
    int*   cursor = (int*)carve((size_t)NN * 4);
    int*   eid_s  = (int*)carve((size_t)ET_ * 4);
    int*   esrc_s = (int*)carve((size_t)ET_ * 4);
    int*   bsum   = (int*)carve(64 * 4);
    __hip_bfloat16* hbuf = (__hip_bfloat16*)carve((size_t)NN * HID_ * 2);
    float* xbuf   = (float*)carve((size_t)NN * HID_ * 4);
    float* als    = (float*)carve((size_t)NN * 5 * 4);
    float* ald    = (float*)carve((size_t)NN * 5 * 4);
    float* pooled = (float*)carve((size_t)GG * HID_ * 4);

    // ---- CSR by destination (rebuilt every call; ws is re-poisoned) ----
    hipMemsetAsync(deg, 0, (size_t)NN * 4, stream);
    k_hist<<<(ET_ + 255) / 256, 256, 0, stream>>>(ei, deg);
    int nb = (NN + 1023) / 1024;
    k_scan1<<<nb, 256, 0, stream>>>(deg, rowptr, bsum);
    k_scan2<<<1, 64, 0, stream>>>(bsum, nb);
    k_scan3<<<(NN + 1 + 255) / 256, 256, 0, stream>>>(rowptr, bsum, cursor);
    k_scatter<<<(ET_ + 255) / 256, 256, 0, stream>>>(ei, cursor, eid_s, esrc_s);

    const int NWB = (NN + 3) / 4;       // wave-per-node blocks (4 waves/block)
    const int GB  = (NN + 63) / 64;     // GEMM blocks

    // ---- layer 1 ----
    k_gemm160v<<<GB, 256, 0, stream>>>(x, W1, nullptr, hbuf, NN, FIN, nullptr, 0);
    k_node_att<<<NWB, 256, 0, stream>>>(hbuf, as1, ad1, als, ald);
    k_edge_softmax<<<NWB, 256, 0, stream>>>(rowptr, eid_s, esrc_s, als, ald, alpha1);
    k_agg_ln<<<NWB, 256, 0, stream>>>(rowptr, eid_s, esrc_s, hbuf, alpha1, b1, ln1s, ln1b, xbuf);

    // ---- layer 2 ----
    k_gemm160v<<<GB, 256, 0, stream>>>(xbuf, W2, nullptr, hbuf, NN, HID_, nullptr, 0);
    k_node_att<<<NWB, 256, 0, stream>>>(hbuf, as2, ad2, als, ald);
    k_edge_softmax<<<NWB, 256, 0, stream>>>(rowptr, eid_s, esrc_s, als, ald, alpha2);
    k_agg_ln<<<NWB, 256, 0, stream>>>(rowptr, eid_s, esrc_s, hbuf, alpha2, b2, ln2s, ln2b, xbuf);

    // ---- readout ----
    k_gemm160v<<<GB, 256, 0, stream>>>(xbuf, Wm, xo, nullptr, NN, HID_, bm, 1);
    hipMemsetAsync(pooled, 0, (size_t)GG * HID_ * 4, stream);
    k_pool<<<dim3(GG, 32), 192, 0, stream>>>(xo, batch, pooled);
    k_mlp<<<1, 256, 0, stream>>>(pooled, batch, Wm1, bm1, ln3s, ln3b, Wm2, bm2, rec);
}

// Round 3
// 762.612 us; speedup vs baseline: 1.5889x; 1.3827x over previous
//
#include <hip/hip_runtime.h>
#include <hip/hip_bf16.h>
#include <cstdint>
#include <cstddef>

#define NN   50000
#define EE   800000
#define ET_  (EE + NN)      // 850000 edges incl. self-loops
#define FIN  500
#define HID_ 160
#define NC_  20
#define GG   8

typedef __attribute__((ext_vector_type(8))) short ab8;   // 8 bf16 (4 VGPRs)
typedef __attribute__((ext_vector_type(4))) float f4;    // MFMA accumulator

static __device__ __forceinline__ unsigned short f2bf(float v) {
    union { float f; uint32_t u; } c; c.f = v;
    uint32_t r = c.u + 0x7FFFu + ((c.u >> 16) & 1u);  // RNE
    return (unsigned short)(r >> 16);
}

static __device__ __forceinline__ int lbound_i(const int* arr, int n, int val) {
    int lo = 0, hi = n;
    while (lo < hi) { int mid = (lo + hi) >> 1; if (arr[mid] < val) lo = mid + 1; else hi = mid; }
    return lo;
}

// ---------------- CSR build ----------------
__global__ __launch_bounds__(256) void k_hist(const int* __restrict__ ei, int* __restrict__ deg) {
    int e = blockIdx.x * 256 + threadIdx.x;
    if (e >= ET_) return;
    int d = (e < EE) ? ei[EE + e] : (e - EE);
    atomicAdd(&deg[d], 1);
}

__global__ __launch_bounds__(256) void k_scan1(const int* __restrict__ deg, int* __restrict__ rowptr,
                                               int* __restrict__ bsum) {
    __shared__ int s[256];
    int t = threadIdx.x;
    int base = blockIdx.x * 1024 + t * 4;
    int v0 = (base + 0 < NN) ? deg[base + 0] : 0;
    int v1 = (base + 1 < NN) ? deg[base + 1] : 0;
    int v2 = (base + 2 < NN) ? deg[base + 2] : 0;
    int v3 = (base + 3 < NN) ? deg[base + 3] : 0;
    int tot = v0 + v1 + v2 + v3;
    s[t] = tot;
    __syncthreads();
    for (int off = 1; off < 256; off <<= 1) {
        int y = (t >= off) ? s[t - off] : 0;
        __syncthreads();
        s[t] += y;
        __syncthreads();
    }
    int excl = s[t] - tot;
    if (t == 255) bsum[blockIdx.x] = s[255];
    if (base + 0 < NN) rowptr[base + 0] = excl;  excl += v0;
    if (base + 1 < NN) rowptr[base + 1] = excl;  excl += v1;
    if (base + 2 < NN) rowptr[base + 2] = excl;  excl += v2;
    if (base + 3 < NN) rowptr[base + 3] = excl;
}

__global__ void k_scan2(int* __restrict__ bsum, int nb) {
    int t = threadIdx.x; // single wave of 64; nb <= 64
    int v = (t < nb) ? bsum[t] : 0;
    int orig = v;
    for (int off = 1; off < 64; off <<= 1) {
        int y = __shfl_up(v, off);
        if (t >= off) v += y;
    }
    if (t < nb) bsum[t] = v - orig; // exclusive prefix
}

__global__ __launch_bounds__(256) void k_scan3(int* __restrict__ rowptr, const int* __restrict__ bsum,
                                               int* __restrict__ cursor) {
    int i = blockIdx.x * 256 + threadIdx.x;
    if (i < NN) {
        int r = rowptr[i] + bsum[i >> 10];
        rowptr[i] = r;
        cursor[i] = r;
    }
    if (i == NN) rowptr[NN] = ET_;
}

__global__ __launch_bounds__(256) void k_scatter(const int* __restrict__ ei, int* __restrict__ cursor,
                                                 int* __restrict__ eid_s, int* __restrict__ esrc_s) {
    int e = blockIdx.x * 256 + threadIdx.x;
    if (e >= ET_) return;
    int s, d;
    if (e < EE) { s = ei[e]; d = ei[EE + e]; } else { s = e - EE; d = e - EE; }
    int slot = atomicAdd(&cursor[d], 1);
    eid_s[slot]  = e;
    esrc_s[slot] = s;
}

// ---------------- weight prep: W[K,160] fp32 -> Wt[160,Kp] bf16 (transposed, zero-pad K) ----
__global__ __launch_bounds__(256) void k_prep_w(const float* __restrict__ W, unsigned short* __restrict__ Wt,
                                                int K, int Kp) {
    int idx = blockIdx.x * 256 + threadIdx.x;
    if (idx >= HID_ * Kp) return;
    int n = idx / Kp, k = idx - n * Kp;
    float v = (k < K) ? W[(size_t)k * HID_ + n] : 0.f;
    Wt[idx] = f2bf(v);
}

// ---------------- MFMA bf16 GEMM: C[M,160] = A[M,K]fp32 @ W[K,160] ----------------
// Bt = W transposed to [160][Kp] bf16. Block: 256 thr (4 waves), tile 128M x 160N.
// Wave w owns M-strips w and w+4 (rows w*16, w*16+64), all 10 N-tiles.
// LDS rows padded 32->40 bf16: every b128 read/write lands bank-uniform.
__global__ __launch_bounds__(256) void k_gemm_mfma(const float* __restrict__ A,
                                                   const unsigned short* __restrict__ Bt,
                                                   float* __restrict__ C, __hip_bfloat16* __restrict__ Cb,
                                                   int M, int K, int Kp,
                                                   const float* __restrict__ bias, int act) {
    __shared__ __align__(16) unsigned short As[128 * 40];  // 10240 B
    __shared__ __align__(16) unsigned short Bs[160 * 40];  // 12800 B
    int tid  = threadIdx.x;
    int lane = tid & 63;
    int w    = tid >> 6;
    int fr   = lane & 15;        // fragment row/col index
    int q8   = (lane >> 4) * 8;  // k-offset of this quad's fragment
    int row0 = blockIdx.x * 128;

    int arow  = tid >> 1;        // 0..127 (A staging row)
    int abase = (tid & 1) * 16;  // col 0 or 16

    f4 acc0[10], acc1[10];
#pragma unroll
    for (int t = 0; t < 10; t++) { acc0[t] = (f4)0.f; acc1[t] = (f4)0.f; }

    for (int k0 = 0; k0 < Kp; k0 += 32) {
        // ---- stage A: 128 rows x 32 cols fp32 -> bf16 ----
        {
            int grow = row0 + arow;
            int bk = k0 + abase;
            unsigned short pk[16];
            if (grow < M && bk + 16 <= K) {
                const float4* src = reinterpret_cast<const float4*>(&A[(size_t)grow * K + bk]);
#pragma unroll
                for (int f = 0; f < 4; f++) {
                    float4 v = src[f];
                    pk[f * 4 + 0] = f2bf(v.x); pk[f * 4 + 1] = f2bf(v.y);
                    pk[f * 4 + 2] = f2bf(v.z); pk[f * 4 + 3] = f2bf(v.w);
                }
            } else {
#pragma unroll
                for (int c = 0; c < 16; c++) {
                    int k = bk + c;
                    pk[c] = (grow < M && k < K) ? f2bf(A[(size_t)grow * K + k]) : (unsigned short)0;
                }
            }
            *reinterpret_cast<ab8*>(&As[arow * 40 + abase])     = *reinterpret_cast<ab8*>(&pk[0]);
            *reinterpret_cast<ab8*>(&As[arow * 40 + abase + 8]) = *reinterpret_cast<ab8*>(&pk[8]);
        }
        // ---- stage B: 160 rows x 32 k-cols bf16 (already transposed) ----
        {
            for (int idx = tid; idx < 640; idx += 256) {
                int n = idx >> 2, c4 = (idx & 3) * 8;
                ab8 v = *reinterpret_cast<const ab8*>(&Bt[(size_t)n * Kp + k0 + c4]);
                *reinterpret_cast<ab8*>(&Bs[n * 40 + c4]) = v;
            }
        }
        __syncthreads();
        ab8 a0 = *reinterpret_cast<const ab8*>(&As[(w * 16 + fr) * 40 + q8]);
        ab8 a1 = *reinterpret_cast<const ab8*>(&As[(w * 16 + 64 + fr) * 40 + q8]);
#pragma unroll
        for (int t = 0; t < 10; t++) {
            ab8 b = *reinterpret_cast<const ab8*>(&Bs[(t * 16 + fr) * 40 + q8]);
            acc0[t] = __builtin_amdgcn_mfma_f32_16x16x32_bf16(a0, b, acc0[t], 0, 0, 0);
            acc1[t] = __builtin_amdgcn_mfma_f32_16x16x32_bf16(a1, b, acc1[t], 0, 0, 0);
        }
        __syncthreads();
    }
    // ---- epilogue: C/D layout col=lane&15, row=(lane>>4)*4+reg ----
    int rbase0 = row0 + w * 16 + (lane >> 4) * 4;
#pragma unroll
    for (int t = 0; t < 10; t++) {
        int col = t * 16 + fr;
        float bv = bias ? bias[col] : 0.f;
#pragma unroll
        for (int i = 0; i < 4; i++) {
            int r0 = rbase0 + i;
            int r1 = r0 + 64;
            float v0 = acc0[t][i] + bv;
            float v1 = acc1[t][i] + bv;
            if (act) { v0 = v0 > 0.f ? v0 : 0.01f * v0; v1 = v1 > 0.f ? v1 : 0.01f * v1; }
            if (r0 < M) {
                if (C)  C[(size_t)r0 * HID_ + col] = v0;
                if (Cb) *reinterpret_cast<unsigned short*>(&Cb[(size_t)r0 * HID_ + col]) = f2bf(v0);
            }
            if (r1 < M) {
                if (C)  C[(size_t)r1 * HID_ + col] = v1;
                if (Cb) *reinterpret_cast<unsigned short*>(&Cb[(size_t)r1 * HID_ + col]) = f2bf(v1);
            }
        }
    }
}

// ---------------- per-node attention coefficients (bf16 h) ----------------
__global__ __launch_bounds__(256) void k_node_att(const __hip_bfloat16* __restrict__ hmat,
                                                  const float* __restrict__ asrc, const float* __restrict__ adst,
                                                  float* __restrict__ als, float* __restrict__ ald) {
    int node = blockIdx.x * 4 + (threadIdx.x >> 6);
    int lane = threadIdx.x & 63;
    if (node >= NN) return;
    const __hip_bfloat16* row = &hmat[(size_t)node * HID_];
    float v0 = __bfloat162float(row[lane]);
    float v1 = __bfloat162float(row[lane + 64]);
    float s0 = v0 * asrc[lane],      d0 = v0 * adst[lane];
    float s1 = v1 * asrc[lane + 64], d1 = v1 * adst[lane + 64];
    float s2 = 0.f, d2 = 0.f;
    if (lane < 32) {
        float v2 = __bfloat162float(row[lane + 128]);
        s2 = v2 * asrc[lane + 128];
        d2 = v2 * adst[lane + 128];
    }
#pragma unroll
    for (int off = 16; off >= 1; off >>= 1) {
        s0 += __shfl_xor(s0, off); s1 += __shfl_xor(s1, off); s2 += __shfl_xor(s2, off);
        d0 += __shfl_xor(d0, off); d1 += __shfl_xor(d1, off); d2 += __shfl_xor(d2, off);
    }
    if (lane == 0) {
        als[node * 5 + 0] = s0; als[node * 5 + 2] = s1; als[node * 5 + 4] = s2;
        ald[node * 5 + 0] = d0; ald[node * 5 + 2] = d1; ald[node * 5 + 4] = d2;
    }
    if (lane == 32) {
        als[node * 5 + 1] = s0; als[node * 5 + 3] = s1;
        ald[node * 5 + 1] = d0; ald[node * 5 + 3] = d1;
    }
}

// ---------------- edge softmax, 2 passes, max-free (logits are O(1); clamp for safety) ----
__global__ __launch_bounds__(256) void k_att_exp(const int* __restrict__ rowptr,
                                                 const int* __restrict__ eid_s, const int* __restrict__ esrc_s,
                                                 const float* __restrict__ als, const float* __restrict__ ald,
                                                 float* __restrict__ alpha) {
    int node = blockIdx.x * 4 + (threadIdx.x >> 6);
    int lane = threadIdx.x & 63;
    if (node >= NN) return;
    int start = rowptr[node], end = rowptr[node + 1];
    float ad[5];
#pragma unroll
    for (int h = 0; h < 5; h++) ad[h] = ald[node * 5 + h];
    float sm[5] = {0.f, 0.f, 0.f, 0.f, 0.f};
    for (int j = start + lane; j < end; j += 64) {
        int src = esrc_s[j];
        int e   = eid_s[j];
        const float* as = &als[(size_t)src * 5];
        float* ap = &alpha[(size_t)e * 5];
#pragma unroll
        for (int h = 0; h < 5; h++) {
            float l = as[h] + ad[h];
            l = l > 0.f ? l : 0.2f * l;
            float ex = __expf(fminf(l, 60.f));
            ap[h] = ex;
            sm[h] += ex;
        }
    }
#pragma unroll
    for (int off = 32; off >= 1; off >>= 1)
#pragma unroll
        for (int h = 0; h < 5; h++) sm[h] += __shfl_xor(sm[h], off);
    float inv[5];
#pragma unroll
    for (int h = 0; h < 5; h++) inv[h] = 1.f / (sm[h] + 1e-16f);
    for (int j = start + lane; j < end; j += 64) {
        int e = eid_s[j];
        float* ap = &alpha[(size_t)e * 5];
#pragma unroll
        for (int h = 0; h < 5; h++) ap[h] *= inv[h];
    }
}

// ---------------- aggregation + bias + leaky(0.01) + LayerNorm (wave per node, bf16 h) ----
__global__ __launch_bounds__(256) void k_agg_ln(const int* __restrict__ rowptr,
                                                const int* __restrict__ eid_s, const int* __restrict__ esrc_s,
                                                const __hip_bfloat16* __restrict__ hmat, const float* __restrict__ alpha,
                                                const float* __restrict__ bias,
                                                const float* __restrict__ lns, const float* __restrict__ lnb,
                                                float* __restrict__ out) {
    int node = blockIdx.x * 4 + (threadIdx.x >> 6);
    int lane = threadIdx.x & 63;
    if (node >= NN) return;
    int start = rowptr[node], end = rowptr[node + 1];
    int h0 = lane >> 5;      // head of channel `lane` (0 or 1)
    int h1 = h0 + 2;         // head of channel lane+64 (2 or 3)
    bool lo32 = lane < 32;
    float a0 = 0.f, a1 = 0.f, a2 = 0.f;
    float c0 = 0.f, c1 = 0.f, c2 = 0.f;
    int j = start;
    for (; j + 1 < end; j += 2) {
        int sA = esrc_s[j], sB = esrc_s[j + 1];
        int eA = eid_s[j],  eB = eid_s[j + 1];
        const float* apA = &alpha[(size_t)eA * 5];
        const float* apB = &alpha[(size_t)eB * 5];
        const __hip_bfloat16* rA = &hmat[(size_t)sA * HID_];
        const __hip_bfloat16* rB = &hmat[(size_t)sB * HID_];
        float wA0 = apA[h0], wA1 = apA[h1];
        float wB0 = apB[h0], wB1 = apB[h1];
        float vA0 = __bfloat162float(rA[lane]);
        float vA1 = __bfloat162float(rA[lane + 64]);
        float vB0 = __bfloat162float(rB[lane]);
        float vB1 = __bfloat162float(rB[lane + 64]);
        a0 += wA0 * vA0; c0 += wB0 * vB0;
        a1 += wA1 * vA1; c1 += wB1 * vB1;
        if (lo32) {
            a2 += apA[4] * __bfloat162float(rA[lane + 128]);
            c2 += apB[4] * __bfloat162float(rB[lane + 128]);
        }
    }
    if (j < end) {
        int src = esrc_s[j];
        int e   = eid_s[j];
        const float* ap  = &alpha[(size_t)e * 5];
        const __hip_bfloat16* row = &hmat[(size_t)src * HID_];
        a0 += ap[h0] * __bfloat162float(row[lane]);
        a1 += ap[h1] * __bfloat162float(row[lane + 64]);
        if (lo32) a2 += ap[4] * __bfloat162float(row[lane + 128]);
    }
    a0 += c0; a1 += c1; a2 += c2;
    float v0 = a0 + bias[lane];       v0 = v0 > 0.f ? v0 : 0.01f * v0;
    float v1 = a1 + bias[lane + 64];  v1 = v1 > 0.f ? v1 : 0.01f * v1;
    float v2 = 0.f;
    if (lo32) { v2 = a2 + bias[lane + 128]; v2 = v2 > 0.f ? v2 : 0.01f * v2; }
    float s  = v0 + v1 + v2;
    float sq = v0 * v0 + v1 * v1 + v2 * v2;
#pragma unroll
    for (int off = 32; off >= 1; off >>= 1) {
        s  += __shfl_xor(s, off);
        sq += __shfl_xor(sq, off);
    }
    float m = s * (1.f / 160.f);
    float r = rsqrtf(sq * (1.f / 160.f) - m * m + 1e-5f);
    size_t ob = (size_t)node * HID_;
    out[ob + lane]       = (v0 - m) * r * lns[lane]       + lnb[lane];
    out[ob + lane + 64]  = (v1 - m) * r * lns[lane + 64]  + lnb[lane + 64];
    if (lo32)
        out[ob + lane + 128] = (v2 - m) * r * lns[lane + 128] + lnb[lane + 128];
}

// ---------------- global mean pool (partial sums, atomic into pooled) ----------------
__global__ __launch_bounds__(192) void k_pool(const float* __restrict__ xo, const int* __restrict__ batch,
                                              float* __restrict__ pooled) {
    int g = blockIdx.x, chunk = blockIdx.y;
    int lo = lbound_i(batch, NN, g), hi = lbound_i(batch, NN, g + 1);
    int len = hi - lo;
    if (len <= 0) return;
    int per = (len + 31) / 32;
    int s = lo + chunk * per;
    int e = min(s + per, hi);
    if (s >= e) return;
    int ch = threadIdx.x;
    if (ch >= HID_) return;
    float acc = 0.f;
    for (int n = s; n < e; n++) acc += xo[(size_t)n * HID_ + ch];
    atomicAdd(&pooled[g * HID_ + ch], acc);
}

// ---------------- readout MLP (single block) ----------------
__global__ __launch_bounds__(256) void k_mlp(const float* __restrict__ pooled, const int* __restrict__ batch,
                                             const float* __restrict__ W1, const float* __restrict__ b1,
                                             const float* __restrict__ lns, const float* __restrict__ lnb,
                                             const float* __restrict__ W2, const float* __restrict__ b2,
                                             float* __restrict__ rec) {
    __shared__ float P[GG][HID_];
    __shared__ float Z[GG][HID_];
    __shared__ float mu[GG], rr[GG], ic[GG];
    int t = threadIdx.x;
    if (t < GG) {
        int lo = lbound_i(batch, NN, t), hi = lbound_i(batch, NN, t + 1);
        ic[t] = 1.f / fmaxf((float)(hi - lo), 1.f);
    }
    __syncthreads();
    for (int i = t; i < GG * HID_; i += 256) P[i / HID_][i % HID_] = pooled[i] * ic[i / HID_];
    __syncthreads();
    for (int i = t; i < GG * HID_; i += 256) {
        int g = i / HID_, j = i % HID_;
        float acc = b1[j];
        for (int k = 0; k < HID_; k++) acc += P[g][k] * W1[k * HID_ + j];
        Z[g][j] = acc;
    }
    __syncthreads();
    if (t < GG) {
        float s = 0.f, sq = 0.f;
        for (int k = 0; k < HID_; k++) { float z = Z[t][k]; s += z; sq += z * z; }
        float m = s / (float)HID_;
        mu[t] = m;
        rr[t] = rsqrtf(sq / (float)HID_ - m * m + 1e-5f);
    }
    __syncthreads();
    for (int i = t; i < GG * HID_; i += 256) {
        int g = i / HID_, j = i % HID_;
        float z = (Z[g][j] - mu[g]) * rr[g] * lns[j] + lnb[j];
        Z[g][j] = fmaxf(z, 0.f);
    }
    __syncthreads();
    for (int i = t; i < GG * NC_; i += 256) {
        int g = i / NC_, j = i % NC_;
        float acc = b2[j];
        for (int k = 0; k < HID_; k++) acc += Z[g][k] * W2[k * NC_ + j];
        rec[g * NC_ + j] = acc;
    }
}

extern "C" void kernel_launch(void* const* d_in, const int* in_sizes, int n_in,
                              void* d_out, int out_size, void* d_ws, size_t ws_size,
                              hipStream_t stream) {
    const float* x    = (const float*)d_in[0];
    const int*   ei   = (const int*)d_in[1];
    const int*   batch= (const int*)d_in[2];
    const float* W1   = (const float*)d_in[3];
    const float* as1  = (const float*)d_in[4];
    const float* ad1  = (const float*)d_in[5];
    const float* b1   = (const float*)d_in[6];
    const float* ln1s = (const float*)d_in[7];
    const float* ln1b = (const float*)d_in[8];
    const float* W2   = (const float*)d_in[9];
    const float* as2  = (const float*)d_in[10];
    const float* ad2  = (const float*)d_in[11];
    const float* b2   = (const float*)d_in[12];
    const float* ln2s = (const float*)d_in[13];
    const float* ln2b = (const float*)d_in[14];
    const float* Wm   = (const float*)d_in[15];
    const float* bm   = (const float*)d_in[16];
    const float* Wm1  = (const float*)d_in[17];
    const float* bm1  = (const float*)d_in[18];
    const float* ln3s = (const float*)d_in[19];
    const float* ln3b = (const float*)d_in[20];
    const float* Wm2  = (const float*)d_in[21];
    const float* bm2  = (const float*)d_in[22];

    float* out    = (float*)d_out;
    float* xo     = out;                              // N*160
    float* rec    = out + (size_t)NN * HID_;          // 8*20
    float* alpha1 = rec + GG * NC_;                   // ET*5
    float* alpha2 = alpha1 + (size_t)ET_ * 5;         // ET*5

    char* w = (char*)d_ws;
    auto carve = [&](size_t bytes) { char* p = w; w += (bytes + 255) & ~(size_t)255; return p; };
    int*   deg    = (int*)carve((size_t)NN * 4);
    int*   rowptr = (int*)carve((size_t)(NN + 1) * 4);
    int*   cursor = (int*)carve((size_t)NN * 4);
    int*   eid_s  = (int*)carve((size_t)ET_ * 4);
    int*   esrc_s = (int*)carve((size_t)ET_ * 4);
    int*   bsum   = (int*)carve(64 * 4);
    __hip_bfloat16* hbuf = (__hip_bfloat16*)carve((size_t)NN * HID_ * 2);
    float* xbuf   = (float*)carve((size_t)NN * HID_ * 4);
    float* als    = (float*)carve((size_t)NN * 5 * 4);
    float* ald    = (float*)carve((size_t)NN * 5 * 4);
    float* pooled = (float*)carve((size_t)GG * HID_ * 4);
    unsigned short* Wt1 = (unsigned short*)carve((size_t)HID_ * 512 * 2);
    unsigned short* Wt2 = (unsigned short*)carve((size_t)HID_ * HID_ * 2);
    unsigned short* Wmt = (unsigned short*)carve((size_t)HID_ * HID_ * 2);

    // ---- CSR by destination (rebuilt every call; ws is re-poisoned) ----
    hipMemsetAsync(deg, 0, (size_t)NN * 4, stream);
    k_hist<<<(ET_ + 255) / 256, 256, 0, stream>>>(ei, deg);
    int nb = (NN + 1023) / 1024;
    k_scan1<<<nb, 256, 0, stream>>>(deg, rowptr, bsum);
    k_scan2<<<1, 64, 0, stream>>>(bsum, nb);
    k_scan3<<<(NN + 1 + 255) / 256, 256, 0, stream>>>(rowptr, bsum, cursor);
    k_scatter<<<(ET_ + 255) / 256, 256, 0, stream>>>(ei, cursor, eid_s, esrc_s);

    // ---- weight prep (bf16 transpose, K zero-padded to mult of 32) ----
    k_prep_w<<<(HID_ * 512 + 255) / 256, 256, 0, stream>>>(W1, Wt1, FIN, 512);
    k_prep_w<<<(HID_ * HID_ + 255) / 256, 256, 0, stream>>>(W2, Wt2, HID_, HID_);
    k_prep_w<<<(HID_ * HID_ + 255) / 256, 256, 0, stream>>>(Wm, Wmt, HID_, HID_);

    const int NWB = (NN + 3) / 4;         // wave-per-node blocks (4 waves/block)
    const int GB  = (NN + 127) / 128;     // MFMA GEMM blocks

    // ---- layer 1 ----
    k_gemm_mfma<<<GB, 256, 0, stream>>>(x, Wt1, nullptr, hbuf, NN, FIN, 512, nullptr, 0);
    k_node_att<<<NWB, 256, 0, stream>>>(hbuf, as1, ad1, als, ald);
    k_att_exp<<<NWB, 256, 0, stream>>>(rowptr, eid_s, esrc_s, als, ald, alpha1);
    k_agg_ln<<<NWB, 256, 0, stream>>>(rowptr, eid_s, esrc_s, hbuf, alpha1, b1, ln1s, ln1b, xbuf);

    // ---- layer 2 ----
    k_gemm_mfma<<<GB, 256, 0, stream>>>(xbuf, Wt2, nullptr, hbuf, NN, HID_, HID_, nullptr, 0);
    k_node_att<<<NWB, 256, 0, stream>>>(hbuf, as2, ad2, als, ald);
    k_att_exp<<<NWB, 256, 0, stream>>>(rowptr, eid_s, esrc_s, als, ald, alpha2);
    k_agg_ln<<<NWB, 256, 0, stream>>>(rowptr, eid_s, esrc_s, hbuf, alpha2, b2, ln2s, ln2b, xbuf);

    // ---- readout ----
    k_gemm_mfma<<<GB, 256, 0, stream>>>(xbuf, Wmt, xo, nullptr, NN, HID_, HID_, bm, 1);
    hipMemsetAsync(pooled, 0, (size_t)GG * HID_ * 4, stream);
    k_pool<<<dim3(GG, 32), 192, 0, stream>>>(xo, batch, pooled);
    k_mlp<<<1, 256, 0, stream>>>(pooled, batch, Wm1, bm1, ln3s, ln3b, Wm2, bm2, rec);
}

// Round 4
// 673.840 us; speedup vs baseline: 1.7982x; 1.1317x over previous
//
#include <hip/hip_runtime.h>
#include <hip/hip_bf16.h>
#include <cstdint>
#include <cstddef>

#define NN   50000
#define EE   800000
#define ET_  (EE + NN)      // 850000 edges incl. self-loops
#define FIN  500
#define HID_ 160
#define NC_  20
#define GG   8

typedef __attribute__((ext_vector_type(8))) short ab8;   // 8 bf16 (4 VGPRs)
typedef __attribute__((ext_vector_type(4))) float f4;    // MFMA accumulator

static __device__ __forceinline__ unsigned short f2bf(float v) {
    union { float f; uint32_t u; } c; c.f = v;
    uint32_t r = c.u + 0x7FFFu + ((c.u >> 16) & 1u);  // RNE
    return (unsigned short)(r >> 16);
}

static __device__ __forceinline__ int lbound_i(const int* arr, int n, int val) {
    int lo = 0, hi = n;
    while (lo < hi) { int mid = (lo + hi) >> 1; if (arr[mid] < val) lo = mid + 1; else hi = mid; }
    return lo;
}

// ---------------- CSR build ----------------
__global__ __launch_bounds__(256) void k_hist(const int* __restrict__ ei, int* __restrict__ deg) {
    int e = blockIdx.x * 256 + threadIdx.x;
    if (e >= ET_) return;
    int d = (e < EE) ? ei[EE + e] : (e - EE);
    atomicAdd(&deg[d], 1);
}

__global__ __launch_bounds__(256) void k_scan1(const int* __restrict__ deg, int* __restrict__ rowptr,
                                               int* __restrict__ bsum) {
    __shared__ int s[256];
    int t = threadIdx.x;
    int base = blockIdx.x * 1024 + t * 4;
    int v0 = (base + 0 < NN) ? deg[base + 0] : 0;
    int v1 = (base + 1 < NN) ? deg[base + 1] : 0;
    int v2 = (base + 2 < NN) ? deg[base + 2] : 0;
    int v3 = (base + 3 < NN) ? deg[base + 3] : 0;
    int tot = v0 + v1 + v2 + v3;
    s[t] = tot;
    __syncthreads();
    for (int off = 1; off < 256; off <<= 1) {
        int y = (t >= off) ? s[t - off] : 0;
        __syncthreads();
        s[t] += y;
        __syncthreads();
    }
    int excl = s[t] - tot;
    if (t == 255) bsum[blockIdx.x] = s[255];
    if (base + 0 < NN) rowptr[base + 0] = excl;  excl += v0;
    if (base + 1 < NN) rowptr[base + 1] = excl;  excl += v1;
    if (base + 2 < NN) rowptr[base + 2] = excl;  excl += v2;
    if (base + 3 < NN) rowptr[base + 3] = excl;
}

__global__ void k_scan2(int* __restrict__ bsum, int nb) {
    int t = threadIdx.x; // single wave of 64; nb <= 64
    int v = (t < nb) ? bsum[t] : 0;
    int orig = v;
    for (int off = 1; off < 64; off <<= 1) {
        int y = __shfl_up(v, off);
        if (t >= off) v += y;
    }
    if (t < nb) bsum[t] = v - orig; // exclusive prefix
}

__global__ __launch_bounds__(256) void k_scan3(int* __restrict__ rowptr, const int* __restrict__ bsum,
                                               int* __restrict__ cursor) {
    int i = blockIdx.x * 256 + threadIdx.x;
    if (i < NN) {
        int r = rowptr[i] + bsum[i >> 10];
        rowptr[i] = r;
        cursor[i] = r;
    }
    if (i == NN) rowptr[NN] = ET_;
}

__global__ __launch_bounds__(256) void k_scatter(const int* __restrict__ ei, int* __restrict__ cursor,
                                                 int2* __restrict__ epair) {
    int e = blockIdx.x * 256 + threadIdx.x;
    if (e >= ET_) return;
    int s, d;
    if (e < EE) { s = ei[e]; d = ei[EE + e]; } else { s = e - EE; d = e - EE; }
    int slot = atomicAdd(&cursor[d], 1);
    epair[slot] = make_int2(e, s);
}

// ---------------- weight prep: W[K,160] fp32 -> Wt[160,Kp] bf16 (transposed, zero-pad K) ----
__global__ __launch_bounds__(256) void k_prep_w(const float* __restrict__ W, unsigned short* __restrict__ Wt,
                                                int K, int Kp) {
    int idx = blockIdx.x * 256 + threadIdx.x;
    if (idx >= HID_ * Kp) return;
    int n = idx / Kp, k = idx - n * Kp;
    float v = (k < K) ? W[(size_t)k * HID_ + n] : 0.f;
    Wt[idx] = f2bf(v);
}

// ---------------- MFMA bf16 GEMM: C[M,160] = A[M,K] @ W[K,160] ----------------
// A is fp32 (a_bf16=0, converted in staging) or bf16 (a_bf16=1, direct copy).
// Bt = W transposed to [160][Kp] bf16. Block: 256 thr (4 waves), tile 128M x 160N.
// LDS rows padded 32->40 bf16: b128 ops land bank-uniform (2-way max = free).
__global__ __launch_bounds__(256) void k_gemm_mfma(const void* __restrict__ Av,
                                                   const unsigned short* __restrict__ Bt,
                                                   float* __restrict__ C, __hip_bfloat16* __restrict__ Cb,
                                                   int M, int K, int Kp, int a_bf16,
                                                   const float* __restrict__ bias, int act) {
    __shared__ __align__(16) unsigned short As[128 * 40];  // 10240 B
    __shared__ __align__(16) unsigned short Bs[160 * 40];  // 12800 B
    int tid  = threadIdx.x;
    int lane = tid & 63;
    int w    = tid >> 6;
    int fr   = lane & 15;        // fragment row/col index
    int q8   = (lane >> 4) * 8;  // k-offset of this quad's fragment
    int row0 = blockIdx.x * 128;

    int arow  = tid >> 1;        // 0..127 (A staging row)
    int abase = (tid & 1) * 16;  // col 0 or 16

    f4 acc0[10], acc1[10];
#pragma unroll
    for (int t = 0; t < 10; t++) { acc0[t] = (f4)0.f; acc1[t] = (f4)0.f; }

    for (int k0 = 0; k0 < Kp; k0 += 32) {
        // ---- stage A tile: 128 rows x 32 cols ----
        {
            int grow = row0 + arow;
            int bk = k0 + abase;
            if (a_bf16) {
                const unsigned short* Ab = (const unsigned short*)Av;
                ab8 v0 = (ab8)0, v1 = (ab8)0;
                if (grow < M) {
                    v0 = *reinterpret_cast<const ab8*>(&Ab[(size_t)grow * K + bk]);
                    v1 = *reinterpret_cast<const ab8*>(&Ab[(size_t)grow * K + bk + 8]);
                }
                *reinterpret_cast<ab8*>(&As[arow * 40 + abase])     = v0;
                *reinterpret_cast<ab8*>(&As[arow * 40 + abase + 8]) = v1;
            } else {
                const float* A = (const float*)Av;
                unsigned short pk[16];
                if (grow < M && bk + 16 <= K) {
                    const float4* src = reinterpret_cast<const float4*>(&A[(size_t)grow * K + bk]);
#pragma unroll
                    for (int f = 0; f < 4; f++) {
                        float4 v = src[f];
                        pk[f * 4 + 0] = f2bf(v.x); pk[f * 4 + 1] = f2bf(v.y);
                        pk[f * 4 + 2] = f2bf(v.z); pk[f * 4 + 3] = f2bf(v.w);
                    }
                } else {
#pragma unroll
                    for (int c = 0; c < 16; c++) {
                        int k = bk + c;
                        pk[c] = (grow < M && k < K) ? f2bf(A[(size_t)grow * K + k]) : (unsigned short)0;
                    }
                }
                *reinterpret_cast<ab8*>(&As[arow * 40 + abase])     = *reinterpret_cast<ab8*>(&pk[0]);
                *reinterpret_cast<ab8*>(&As[arow * 40 + abase + 8]) = *reinterpret_cast<ab8*>(&pk[8]);
            }
        }
        // ---- stage B: 160 rows x 32 k-cols bf16 (already transposed) ----
        {
            for (int idx = tid; idx < 640; idx += 256) {
                int n = idx >> 2, c4 = (idx & 3) * 8;
                ab8 v = *reinterpret_cast<const ab8*>(&Bt[(size_t)n * Kp + k0 + c4]);
                *reinterpret_cast<ab8*>(&Bs[n * 40 + c4]) = v;
            }
        }
        __syncthreads();
        ab8 a0 = *reinterpret_cast<const ab8*>(&As[(w * 16 + fr) * 40 + q8]);
        ab8 a1 = *reinterpret_cast<const ab8*>(&As[(w * 16 + 64 + fr) * 40 + q8]);
#pragma unroll
        for (int t = 0; t < 10; t++) {
            ab8 b = *reinterpret_cast<const ab8*>(&Bs[(t * 16 + fr) * 40 + q8]);
            acc0[t] = __builtin_amdgcn_mfma_f32_16x16x32_bf16(a0, b, acc0[t], 0, 0, 0);
            acc1[t] = __builtin_amdgcn_mfma_f32_16x16x32_bf16(a1, b, acc1[t], 0, 0, 0);
        }
        __syncthreads();
    }
    // ---- epilogue: C/D layout col=lane&15, row=(lane>>4)*4+reg ----
    int rbase0 = row0 + w * 16 + (lane >> 4) * 4;
#pragma unroll
    for (int t = 0; t < 10; t++) {
        int col = t * 16 + fr;
        float bv = bias ? bias[col] : 0.f;
#pragma unroll
        for (int i = 0; i < 4; i++) {
            int r0 = rbase0 + i;
            int r1 = r0 + 64;
            float v0 = acc0[t][i] + bv;
            float v1 = acc1[t][i] + bv;
            if (act) { v0 = v0 > 0.f ? v0 : 0.01f * v0; v1 = v1 > 0.f ? v1 : 0.01f * v1; }
            if (r0 < M) {
                if (C)  C[(size_t)r0 * HID_ + col] = v0;
                if (Cb) *reinterpret_cast<unsigned short*>(&Cb[(size_t)r0 * HID_ + col]) = f2bf(v0);
            }
            if (r1 < M) {
                if (C)  C[(size_t)r1 * HID_ + col] = v1;
                if (Cb) *reinterpret_cast<unsigned short*>(&Cb[(size_t)r1 * HID_ + col]) = f2bf(v1);
            }
        }
    }
}

// ---------------- per-node attention coefficients (bf16 h) ----------------
__global__ __launch_bounds__(256) void k_node_att(const __hip_bfloat16* __restrict__ hmat,
                                                  const float* __restrict__ asrc, const float* __restrict__ adst,
                                                  float* __restrict__ als, float* __restrict__ ald) {
    int node = blockIdx.x * 4 + (threadIdx.x >> 6);
    int lane = threadIdx.x & 63;
    if (node >= NN) return;
    const __hip_bfloat16* row = &hmat[(size_t)node * HID_];
    float v0 = __bfloat162float(row[lane]);
    float v1 = __bfloat162float(row[lane + 64]);
    float s0 = v0 * asrc[lane],      d0 = v0 * adst[lane];
    float s1 = v1 * asrc[lane + 64], d1 = v1 * adst[lane + 64];
    float s2 = 0.f, d2 = 0.f;
    if (lane < 32) {
        float v2 = __bfloat162float(row[lane + 128]);
        s2 = v2 * asrc[lane + 128];
        d2 = v2 * adst[lane + 128];
    }
#pragma unroll
    for (int off = 16; off >= 1; off >>= 1) {
        s0 += __shfl_xor(s0, off); s1 += __shfl_xor(s1, off); s2 += __shfl_xor(s2, off);
        d0 += __shfl_xor(d0, off); d1 += __shfl_xor(d1, off); d2 += __shfl_xor(d2, off);
    }
    if (lane == 0) {
        als[node * 5 + 0] = s0; als[node * 5 + 2] = s1; als[node * 5 + 4] = s2;
        ald[node * 5 + 0] = d0; ald[node * 5 + 2] = d1; ald[node * 5 + 4] = d2;
    }
    if (lane == 32) {
        als[node * 5 + 1] = s0; als[node * 5 + 3] = s1;
        ald[node * 5 + 1] = d0; ald[node * 5 + 3] = d1;
    }
}

// ---------- fused edge softmax + aggregation + bias + leaky + LayerNorm ----------
// One wave per destination node. Edge list + un-normalized exp cached in LDS
// (deg <= 64 fast path; global alphap fallback otherwise). Emits:
//  - normalized alpha scattered to output (edge-id order)
//  - bf16 LayerNorm'd node features
__global__ __launch_bounds__(256) void k_att_agg(const int* __restrict__ rowptr,
                                                 const int2* __restrict__ epair,
                                                 const float* __restrict__ als, const float* __restrict__ ald,
                                                 const __hip_bfloat16* __restrict__ hmat,
                                                 float* __restrict__ alphap,      // [ET_*5] overflow scratch
                                                 float* __restrict__ alpha_out,   // [ET_*5] edge-id order
                                                 const float* __restrict__ bias,
                                                 const float* __restrict__ lns, const float* __restrict__ lnb,
                                                 __hip_bfloat16* __restrict__ outb) {
    __shared__ float sExp[4][64 * 5];
    __shared__ int2  sPair[4][64];
    int wv   = threadIdx.x >> 6;
    int lane = threadIdx.x & 63;
    int node = blockIdx.x * 4 + wv;
    if (node >= NN) return;
    int start = rowptr[node], end = rowptr[node + 1];
    int deg = end - start;
    bool fits = (deg <= 64);
    float ad[5];
#pragma unroll
    for (int h = 0; h < 5; h++) ad[h] = ald[node * 5 + h];

    // ---- pass 1: exp(leaky(logit)), lane-parallel ----
    float sm[5] = {0.f, 0.f, 0.f, 0.f, 0.f};
    for (int j = start + lane; j < end; j += 64) {
        int2 p = epair[j];
        const float* as = &als[(size_t)p.y * 5];
        int idx = j - start;
        if (fits) sPair[wv][idx] = p;
#pragma unroll
        for (int h = 0; h < 5; h++) {
            float l = as[h] + ad[h];
            l = l > 0.f ? l : 0.2f * l;
            float ex = __expf(fminf(l, 60.f));
            sm[h] += ex;
            if (fits) sExp[wv][idx * 5 + h] = ex;
            else      alphap[(size_t)j * 5 + h] = ex;
        }
    }
#pragma unroll
    for (int off = 32; off >= 1; off >>= 1)
#pragma unroll
        for (int h = 0; h < 5; h++) sm[h] += __shfl_xor(sm[h], off);
    float inv[5];
#pragma unroll
    for (int h = 0; h < 5; h++) inv[h] = 1.f / (sm[h] + 1e-16f);

    int h0 = lane >> 5;      // head of channel `lane` (0 or 1)
    int h1 = h0 + 2;         // head of channel lane+64 (2 or 3)
    bool lo32 = lane < 32;
    float a0 = 0.f, a1 = 0.f, a2 = 0.f;
    float c0 = 0.f, c1 = 0.f, c2 = 0.f;

    if (fits) {
        // ---- scatter normalized alpha (lane-parallel) ----
        if (lane < deg) {
            int2 p = sPair[wv][lane];
            float* ao = &alpha_out[(size_t)p.x * 5];
#pragma unroll
            for (int h = 0; h < 5; h++) ao[h] = sExp[wv][lane * 5 + h] * inv[h];
        }
        // ---- aggregation: serial over edges, channels across lanes ----
        int idx = 0;
        for (; idx + 1 < deg; idx += 2) {
            int2 pA = sPair[wv][idx], pB = sPair[wv][idx + 1];
            float wA0 = sExp[wv][idx * 5 + h0] * inv[h0];
            float wA1 = sExp[wv][idx * 5 + h1] * inv[h1];
            float wB0 = sExp[wv][(idx + 1) * 5 + h0] * inv[h0];
            float wB1 = sExp[wv][(idx + 1) * 5 + h1] * inv[h1];
            const __hip_bfloat16* rA = &hmat[(size_t)pA.y * HID_];
            const __hip_bfloat16* rB = &hmat[(size_t)pB.y * HID_];
            float vA0 = __bfloat162float(rA[lane]);
            float vA1 = __bfloat162float(rA[lane + 64]);
            float vB0 = __bfloat162float(rB[lane]);
            float vB1 = __bfloat162float(rB[lane + 64]);
            a0 += wA0 * vA0; c0 += wB0 * vB0;
            a1 += wA1 * vA1; c1 += wB1 * vB1;
            if (lo32) {
                a2 += sExp[wv][idx * 5 + 4] * inv[4] * __bfloat162float(rA[lane + 128]);
                c2 += sExp[wv][(idx + 1) * 5 + 4] * inv[4] * __bfloat162float(rB[lane + 128]);
            }
        }
        if (idx < deg) {
            int2 p = sPair[wv][idx];
            float w0 = sExp[wv][idx * 5 + h0] * inv[h0];
            float w1 = sExp[wv][idx * 5 + h1] * inv[h1];
            const __hip_bfloat16* row = &hmat[(size_t)p.y * HID_];
            a0 += w0 * __bfloat162float(row[lane]);
            a1 += w1 * __bfloat162float(row[lane + 64]);
            if (lo32) a2 += sExp[wv][idx * 5 + 4] * inv[4] * __bfloat162float(row[lane + 128]);
        }
    } else {
        // ---- overflow path (deg > 64): alpha staged in global scratch ----
        for (int j = start + lane; j < end; j += 64) {
            int2 p = epair[j];
            float* ao = &alpha_out[(size_t)p.x * 5];
#pragma unroll
            for (int h = 0; h < 5; h++) ao[h] = alphap[(size_t)j * 5 + h] * inv[h];
        }
        for (int j = start; j < end; j++) {
            int2 p = epair[j];
            const float* ap = &alphap[(size_t)j * 5];
            const __hip_bfloat16* row = &hmat[(size_t)p.y * HID_];
            a0 += ap[h0] * inv[h0] * __bfloat162float(row[lane]);
            a1 += ap[h1] * inv[h1] * __bfloat162float(row[lane + 64]);
            if (lo32) a2 += ap[4] * inv[4] * __bfloat162float(row[lane + 128]);
        }
    }
    a0 += c0; a1 += c1; a2 += c2;

    // ---- bias + leaky(0.01) + LayerNorm ----
    float v0 = a0 + bias[lane];       v0 = v0 > 0.f ? v0 : 0.01f * v0;
    float v1 = a1 + bias[lane + 64];  v1 = v1 > 0.f ? v1 : 0.01f * v1;
    float v2 = 0.f;
    if (lo32) { v2 = a2 + bias[lane + 128]; v2 = v2 > 0.f ? v2 : 0.01f * v2; }
    float s  = v0 + v1 + v2;
    float sq = v0 * v0 + v1 * v1 + v2 * v2;
#pragma unroll
    for (int off = 32; off >= 1; off >>= 1) {
        s  += __shfl_xor(s, off);
        sq += __shfl_xor(sq, off);
    }
    float m = s * (1.f / 160.f);
    float r = rsqrtf(sq * (1.f / 160.f) - m * m + 1e-5f);
    size_t ob = (size_t)node * HID_;
    outb[ob + lane]      = __hip_bfloat16_raw{f2bf((v0 - m) * r * lns[lane]      + lnb[lane])};
    outb[ob + lane + 64] = __hip_bfloat16_raw{f2bf((v1 - m) * r * lns[lane + 64] + lnb[lane + 64])};
    if (lo32)
        outb[ob + lane + 128] = __hip_bfloat16_raw{f2bf((v2 - m) * r * lns[lane + 128] + lnb[lane + 128])};
}

// ---------------- global mean pool (partial sums, atomic into pooled) ----------------
__global__ __launch_bounds__(192) void k_pool(const float* __restrict__ xo, const int* __restrict__ batch,
                                              float* __restrict__ pooled) {
    int g = blockIdx.x, chunk = blockIdx.y;
    int lo = lbound_i(batch, NN, g), hi = lbound_i(batch, NN, g + 1);
    int len = hi - lo;
    if (len <= 0) return;
    int per = (len + 31) / 32;
    int s = lo + chunk * per;
    int e = min(s + per, hi);
    if (s >= e) return;
    int ch = threadIdx.x;
    if (ch >= HID_) return;
    float acc = 0.f;
    for (int n = s; n < e; n++) acc += xo[(size_t)n * HID_ + ch];
    atomicAdd(&pooled[g * HID_ + ch], acc);
}

// ---------------- readout MLP (single block) ----------------
__global__ __launch_bounds__(256) void k_mlp(const float* __restrict__ pooled, const int* __restrict__ batch,
                                             const float* __restrict__ W1, const float* __restrict__ b1,
                                             const float* __restrict__ lns, const float* __restrict__ lnb,
                                             const float* __restrict__ W2, const float* __restrict__ b2,
                                             float* __restrict__ rec) {
    __shared__ float P[GG][HID_];
    __shared__ float Z[GG][HID_];
    __shared__ float mu[GG], rr[GG], ic[GG];
    int t = threadIdx.x;
    if (t < GG) {
        int lo = lbound_i(batch, NN, t), hi = lbound_i(batch, NN, t + 1);
        ic[t] = 1.f / fmaxf((float)(hi - lo), 1.f);
    }
    __syncthreads();
    for (int i = t; i < GG * HID_; i += 256) P[i / HID_][i % HID_] = pooled[i] * ic[i / HID_];
    __syncthreads();
    for (int i = t; i < GG * HID_; i += 256) {
        int g = i / HID_, j = i % HID_;
        float acc = b1[j];
        for (int k = 0; k < HID_; k++) acc += P[g][k] * W1[k * HID_ + j];
        Z[g][j] = acc;
    }
    __syncthreads();
    if (t < GG) {
        float s = 0.f, sq = 0.f;
        for (int k = 0; k < HID_; k++) { float z = Z[t][k]; s += z; sq += z * z; }
        float m = s / (float)HID_;
        mu[t] = m;
        rr[t] = rsqrtf(sq / (float)HID_ - m * m + 1e-5f);
    }
    __syncthreads();
    for (int i = t; i < GG * HID_; i += 256) {
        int g = i / HID_, j = i % HID_;
        float z = (Z[g][j] - mu[g]) * rr[g] * lns[j] + lnb[j];
        Z[g][j] = fmaxf(z, 0.f);
    }
    __syncthreads();
    for (int i = t; i < GG * NC_; i += 256) {
        int g = i / NC_, j = i % NC_;
        float acc = b2[j];
        for (int k = 0; k < HID_; k++) acc += Z[g][k] * W2[k * NC_ + j];
        rec[g * NC_ + j] = acc;
    }
}

extern "C" void kernel_launch(void* const* d_in, const int* in_sizes, int n_in,
                              void* d_out, int out_size, void* d_ws, size_t ws_size,
                              hipStream_t stream) {
    const float* x    = (const float*)d_in[0];
    const int*   ei   = (const int*)d_in[1];
    const int*   batch= (const int*)d_in[2];
    const float* W1   = (const float*)d_in[3];
    const float* as1  = (const float*)d_in[4];
    const float* ad1  = (const float*)d_in[5];
    const float* b1   = (const float*)d_in[6];
    const float* ln1s = (const float*)d_in[7];
    const float* ln1b = (const float*)d_in[8];
    const float* W2   = (const float*)d_in[9];
    const float* as2  = (const float*)d_in[10];
    const float* ad2  = (const float*)d_in[11];
    const float* b2   = (const float*)d_in[12];
    const float* ln2s = (const float*)d_in[13];
    const float* ln2b = (const float*)d_in[14];
    const float* Wm   = (const float*)d_in[15];
    const float* bm   = (const float*)d_in[16];
    const float* Wm1  = (const float*)d_in[17];
    const float* bm1  = (const float*)d_in[18];
    const float* ln3s = (const float*)d_in[19];
    const float* ln3b = (const float*)d_in[20];
    const float* Wm2  = (const float*)d_in[21];
    const float* bm2  = (const float*)d_in[22];

    float* out    = (float*)d_out;
    float* xo     = out;                              // N*160
    float* rec    = out + (size_t)NN * HID_;          // 8*20
    float* alpha1 = rec + GG * NC_;                   // ET*5
    float* alpha2 = alpha1 + (size_t)ET_ * 5;         // ET*5

    char* w = (char*)d_ws;
    auto carve = [&](size_t bytes) { char* p = w; w += (bytes + 255) & ~(size_t)255; return p; };
    int*   deg    = (int*)carve((size_t)NN * 4);
    int*   rowptr = (int*)carve((size_t)(NN + 1) * 4);
    int*   cursor = (int*)carve((size_t)NN * 4);
    int2*  epair  = (int2*)carve((size_t)ET_ * 8);
    int*   bsum   = (int*)carve(64 * 4);
    __hip_bfloat16* hbuf  = (__hip_bfloat16*)carve((size_t)NN * HID_ * 2);
    __hip_bfloat16* xbufb = (__hip_bfloat16*)carve((size_t)NN * HID_ * 2);
    float* alphap = (float*)carve((size_t)ET_ * 5 * 4);
    float* als    = (float*)carve((size_t)NN * 5 * 4);
    float* ald    = (float*)carve((size_t)NN * 5 * 4);
    float* pooled = (float*)carve((size_t)GG * HID_ * 4);
    unsigned short* Wt1 = (unsigned short*)carve((size_t)HID_ * 512 * 2);
    unsigned short* Wt2 = (unsigned short*)carve((size_t)HID_ * HID_ * 2);
    unsigned short* Wmt = (unsigned short*)carve((size_t)HID_ * HID_ * 2);

    // ---- CSR by destination (rebuilt every call; ws is re-poisoned) ----
    hipMemsetAsync(deg, 0, (size_t)NN * 4, stream);
    k_hist<<<(ET_ + 255) / 256, 256, 0, stream>>>(ei, deg);
    int nb = (NN + 1023) / 1024;
    k_scan1<<<nb, 256, 0, stream>>>(deg, rowptr, bsum);
    k_scan2<<<1, 64, 0, stream>>>(bsum, nb);
    k_scan3<<<(NN + 1 + 255) / 256, 256, 0, stream>>>(rowptr, bsum, cursor);
    k_scatter<<<(ET_ + 255) / 256, 256, 0, stream>>>(ei, cursor, epair);

    // ---- weight prep (bf16 transpose, K zero-padded to mult of 32) ----
    k_prep_w<<<(HID_ * 512 + 255) / 256, 256, 0, stream>>>(W1, Wt1, FIN, 512);
    k_prep_w<<<(HID_ * HID_ + 255) / 256, 256, 0, stream>>>(W2, Wt2, HID_, HID_);
    k_prep_w<<<(HID_ * HID_ + 255) / 256, 256, 0, stream>>>(Wm, Wmt, HID_, HID_);

    const int NWB = (NN + 3) / 4;         // wave-per-node blocks (4 waves/block)
    const int GB  = (NN + 127) / 128;     // MFMA GEMM blocks

    // ---- layer 1 ----
    k_gemm_mfma<<<GB, 256, 0, stream>>>(x, Wt1, nullptr, hbuf, NN, FIN, 512, 0, nullptr, 0);
    k_node_att<<<NWB, 256, 0, stream>>>(hbuf, as1, ad1, als, ald);
    k_att_agg<<<NWB, 256, 0, stream>>>(rowptr, epair, als, ald, hbuf, alphap, alpha1,
                                       b1, ln1s, ln1b, xbufb);

    // ---- layer 2 ----
    k_gemm_mfma<<<GB, 256, 0, stream>>>(xbufb, Wt2, nullptr, hbuf, NN, HID_, HID_, 1, nullptr, 0);
    k_node_att<<<NWB, 256, 0, stream>>>(hbuf, as2, ad2, als, ald);
    k_att_agg<<<NWB, 256, 0, stream>>>(rowptr, epair, als, ald, hbuf, alphap, alpha2,
                                       b2, ln2s, ln2b, xbufb);

    // ---- readout ----
    k_gemm_mfma<<<GB, 256, 0, stream>>>(xbufb, Wmt, xo, nullptr, NN, HID_, HID_, 1, bm, 1);
    hipMemsetAsync(pooled, 0, (size_t)GG * HID_ * 4, stream);
    k_pool<<<dim3(GG, 32), 192, 0, stream>>>(xo, batch, pooled);
    k_mlp<<<1, 256, 0, stream>>>(pooled, batch, Wm1, bm1, ln3s, ln3b, Wm2, bm2, rec);
}

// Round 6
// 665.369 us; speedup vs baseline: 1.8211x; 1.0127x over previous
//
#include <hip/hip_runtime.h>
#include <hip/hip_bf16.h>
#include <cstdint>
#include <cstddef>

#define NN   50000
#define EE   800000
#define ET_  (EE + NN)      // 850000 edges incl. self-loops
#define FIN  500
#define HID_ 160
#define NC_  20
#define GG   8

typedef __attribute__((ext_vector_type(8))) short ab8;   // 8 bf16 (4 VGPRs)
typedef __attribute__((ext_vector_type(4))) float f4;    // MFMA accumulator

static __device__ __forceinline__ unsigned short f2bf(float v) {
    union { float f; uint32_t u; } c; c.f = v;
    uint32_t r = c.u + 0x7FFFu + ((c.u >> 16) & 1u);  // RNE
    return (unsigned short)(r >> 16);
}

static __device__ __forceinline__ float2 bf2f2(uint32_t u) {
    // u holds bf16 pair (lo = even ch, hi = odd ch)
    union { uint32_t u; float f; } a, b;
    a.u = u << 16;
    b.u = u & 0xffff0000u;
    return make_float2(a.f, b.f);
}

static __device__ __forceinline__ int lbound_i(const int* arr, int n, int val) {
    int lo = 0, hi = n;
    while (lo < hi) { int mid = (lo + hi) >> 1; if (arr[mid] < val) lo = mid + 1; else hi = mid; }
    return lo;
}

// ---------------- CSR build ----------------
__global__ __launch_bounds__(256) void k_hist(const int* __restrict__ ei, int* __restrict__ deg) {
    int e = blockIdx.x * 256 + threadIdx.x;
    if (e >= ET_) return;
    int d = (e < EE) ? ei[EE + e] : (e - EE);
    atomicAdd(&deg[d], 1);
}

__global__ __launch_bounds__(256) void k_scan1(const int* __restrict__ deg, int* __restrict__ rowptr,
                                               int* __restrict__ bsum) {
    __shared__ int s[256];
    int t = threadIdx.x;
    int base = blockIdx.x * 1024 + t * 4;
    int v0 = (base + 0 < NN) ? deg[base + 0] : 0;
    int v1 = (base + 1 < NN) ? deg[base + 1] : 0;
    int v2 = (base + 2 < NN) ? deg[base + 2] : 0;
    int v3 = (base + 3 < NN) ? deg[base + 3] : 0;
    int tot = v0 + v1 + v2 + v3;
    s[t] = tot;
    __syncthreads();
    for (int off = 1; off < 256; off <<= 1) {
        int y = (t >= off) ? s[t - off] : 0;
        __syncthreads();
        s[t] += y;
        __syncthreads();
    }
    int excl = s[t] - tot;
    if (t == 255) bsum[blockIdx.x] = s[255];
    if (base + 0 < NN) rowptr[base + 0] = excl;  excl += v0;
    if (base + 1 < NN) rowptr[base + 1] = excl;  excl += v1;
    if (base + 2 < NN) rowptr[base + 2] = excl;  excl += v2;
    if (base + 3 < NN) rowptr[base + 3] = excl;
}

__global__ void k_scan2(int* __restrict__ bsum, int nb) {
    int t = threadIdx.x; // single wave of 64; nb <= 64
    int v = (t < nb) ? bsum[t] : 0;
    int orig = v;
    for (int off = 1; off < 64; off <<= 1) {
        int y = __shfl_up(v, off);
        if (t >= off) v += y;
    }
    if (t < nb) bsum[t] = v - orig; // exclusive prefix
}

__global__ __launch_bounds__(256) void k_scan3(int* __restrict__ rowptr, const int* __restrict__ bsum,
                                               int* __restrict__ cursor) {
    int i = blockIdx.x * 256 + threadIdx.x;
    if (i < NN) {
        int r = rowptr[i] + bsum[i >> 10];
        rowptr[i] = r;
        cursor[i] = r;
    }
    if (i == NN) rowptr[NN] = ET_;
}

__global__ __launch_bounds__(256) void k_scatter(const int* __restrict__ ei, int* __restrict__ cursor,
                                                 int2* __restrict__ epair) {
    int e = blockIdx.x * 256 + threadIdx.x;
    if (e >= ET_) return;
    int s, d;
    if (e < EE) { s = ei[e]; d = ei[EE + e]; } else { s = e - EE; d = e - EE; }
    int slot = atomicAdd(&cursor[d], 1);
    epair[slot] = make_int2(e, s);
}

// ---------------- weight prep: three weights in one launch ----------------
// W[K,160] fp32 -> Wt[160,Kp] bf16 (transposed, zero-pad K)
__global__ __launch_bounds__(256) void k_prep_all(const float* __restrict__ W1, unsigned short* __restrict__ Wt1,
                                                  const float* __restrict__ W2, unsigned short* __restrict__ Wt2,
                                                  const float* __restrict__ Wm, unsigned short* __restrict__ Wmt) {
    int idx = blockIdx.x * 256 + threadIdx.x;
    const int S1 = HID_ * 512, S2 = HID_ * HID_;
    if (idx < S1) {
        int n = idx / 512, k = idx - n * 512;
        Wt1[idx] = (k < FIN) ? f2bf(W1[(size_t)k * HID_ + n]) : (unsigned short)0;
    } else if (idx < S1 + S2) {
        int j = idx - S1;
        int n = j / HID_, k = j - n * HID_;
        Wt2[j] = f2bf(W2[(size_t)k * HID_ + n]);
    } else if (idx < S1 + 2 * S2) {
        int j = idx - S1 - S2;
        int n = j / HID_, k = j - n * HID_;
        Wmt[j] = f2bf(Wm[(size_t)k * HID_ + n]);
    }
}

// ---------------- MFMA bf16 GEMM: C[M,160] = A[M,K] @ W[K,160] ----------------
// A fp32 (a_bf16=0, converted in staging) or bf16 (a_bf16=1). Bt = W^T [160][Kp] bf16.
// Block: 256 thr (4 waves), tile 128M x 160N. LDS rows padded 32->40 bf16.
// Optional fused epilogues:
//  - asrc/adst + als/ald: per-row per-head attention dots (GAT layers)
//  - batch+pooled: global mean-pool partial sums (readout GEMM)
__global__ __launch_bounds__(256) void k_gemm_mfma(const void* __restrict__ Av,
                                                   const unsigned short* __restrict__ Bt,
                                                   float* __restrict__ C, __hip_bfloat16* __restrict__ Cb,
                                                   int M, int K, int Kp, int a_bf16,
                                                   const float* __restrict__ bias, int act,
                                                   const float* __restrict__ asrc, const float* __restrict__ adst,
                                                   float* __restrict__ als_o, float* __restrict__ ald_o,
                                                   const int* __restrict__ batch_p, float* __restrict__ pooled) {
    __shared__ __align__(16) unsigned short As[128 * 40];  // 10240 B
    __shared__ __align__(16) unsigned short Bs[160 * 40];  // 12800 B
    int tid  = threadIdx.x;
    int lane = tid & 63;
    int w    = tid >> 6;
    int fr   = lane & 15;        // fragment row/col index
    int q8   = (lane >> 4) * 8;  // k-offset of this quad's fragment
    int row0 = blockIdx.x * 128;

    int arow  = tid >> 1;        // 0..127 (A staging row)
    int abase = (tid & 1) * 16;  // col 0 or 16

    f4 acc0[10], acc1[10];
#pragma unroll
    for (int t = 0; t < 10; t++) { acc0[t] = (f4)0.f; acc1[t] = (f4)0.f; }

    for (int k0 = 0; k0 < Kp; k0 += 32) {
        // ---- stage A tile: 128 rows x 32 cols ----
        {
            int grow = row0 + arow;
            int bk = k0 + abase;
            if (a_bf16) {
                const unsigned short* Ab = (const unsigned short*)Av;
                ab8 v0 = (ab8)0, v1 = (ab8)0;
                if (grow < M) {
                    v0 = *reinterpret_cast<const ab8*>(&Ab[(size_t)grow * K + bk]);
                    v1 = *reinterpret_cast<const ab8*>(&Ab[(size_t)grow * K + bk + 8]);
                }
                *reinterpret_cast<ab8*>(&As[arow * 40 + abase])     = v0;
                *reinterpret_cast<ab8*>(&As[arow * 40 + abase + 8]) = v1;
            } else {
                const float* A = (const float*)Av;
                unsigned short pk[16];
                if (grow < M && bk + 16 <= K) {
                    const float4* src = reinterpret_cast<const float4*>(&A[(size_t)grow * K + bk]);
#pragma unroll
                    for (int f = 0; f < 4; f++) {
                        float4 v = src[f];
                        pk[f * 4 + 0] = f2bf(v.x); pk[f * 4 + 1] = f2bf(v.y);
                        pk[f * 4 + 2] = f2bf(v.z); pk[f * 4 + 3] = f2bf(v.w);
                    }
                } else {
#pragma unroll
                    for (int c = 0; c < 16; c++) {
                        int k = bk + c;
                        pk[c] = (grow < M && k < K) ? f2bf(A[(size_t)grow * K + k]) : (unsigned short)0;
                    }
                }
                *reinterpret_cast<ab8*>(&As[arow * 40 + abase])     = *reinterpret_cast<ab8*>(&pk[0]);
                *reinterpret_cast<ab8*>(&As[arow * 40 + abase + 8]) = *reinterpret_cast<ab8*>(&pk[8]);
            }
        }
        // ---- stage B: 160 rows x 32 k-cols bf16 (already transposed) ----
        {
            for (int idx = tid; idx < 640; idx += 256) {
                int n = idx >> 2, c4 = (idx & 3) * 8;
                ab8 v = *reinterpret_cast<const ab8*>(&Bt[(size_t)n * Kp + k0 + c4]);
                *reinterpret_cast<ab8*>(&Bs[n * 40 + c4]) = v;
            }
        }
        __syncthreads();
        ab8 a0 = *reinterpret_cast<const ab8*>(&As[(w * 16 + fr) * 40 + q8]);
        ab8 a1 = *reinterpret_cast<const ab8*>(&As[(w * 16 + 64 + fr) * 40 + q8]);
#pragma unroll
        for (int t = 0; t < 10; t++) {
            ab8 b = *reinterpret_cast<const ab8*>(&Bs[(t * 16 + fr) * 40 + q8]);
            acc0[t] = __builtin_amdgcn_mfma_f32_16x16x32_bf16(a0, b, acc0[t], 0, 0, 0);
            acc1[t] = __builtin_amdgcn_mfma_f32_16x16x32_bf16(a1, b, acc1[t], 0, 0, 0);
        }
        __syncthreads();
    }

    int q = lane >> 4;
    // ---- fused per-node attention dots: als/ald (GAT layers) ----
    if (als_o) {
        float av_s[10], av_d[10];
#pragma unroll
        for (int t = 0; t < 10; t++) { av_s[t] = asrc[t * 16 + fr]; av_d[t] = adst[t * 16 + fr]; }
#pragma unroll
        for (int s = 0; s < 2; s++) {
            const f4* ac = s ? acc1 : acc0;
#pragma unroll
            for (int i = 0; i < 4; i++) {
                int r = row0 + w * 16 + q * 4 + i + s * 64;
                float ps[5], pd[5];
#pragma unroll
                for (int h = 0; h < 5; h++) {
                    ps[h] = ac[2 * h][i] * av_s[2 * h] + ac[2 * h + 1][i] * av_s[2 * h + 1];
                    pd[h] = ac[2 * h][i] * av_d[2 * h] + ac[2 * h + 1][i] * av_d[2 * h + 1];
                }
#pragma unroll
                for (int off = 8; off >= 1; off >>= 1)
#pragma unroll
                    for (int h = 0; h < 5; h++) {
                        ps[h] += __shfl_xor(ps[h], off);
                        pd[h] += __shfl_xor(pd[h], off);
                    }
                if (fr == 0 && r < M) {
#pragma unroll
                    for (int h = 0; h < 5; h++) {
                        als_o[(size_t)r * 5 + h] = ps[h];
                        ald_o[(size_t)r * 5 + h] = pd[h];
                    }
                }
            }
        }
    }

    // ---- pool setup (readout GEMM): block-uniform-graph fast path ----
    int gu = -2;
    if (pooled) {
        int gl = batch_p[row0];
        int rhi = row0 + 127; if (rhi >= M) rhi = M - 1;
        int gh = batch_p[rhi];
        gu = (gl == gh) ? gl : -1;
    }
    float psum[10];
#pragma unroll
    for (int t = 0; t < 10; t++) psum[t] = 0.f;

    // ---- epilogue: C/D layout col=lane&15, row=(lane>>4)*4+reg ----
    int rbase0 = row0 + w * 16 + q * 4;
#pragma unroll
    for (int t = 0; t < 10; t++) {
        int col = t * 16 + fr;
        float bv = bias ? bias[col] : 0.f;
#pragma unroll
        for (int i = 0; i < 4; i++) {
            int r0 = rbase0 + i;
            int r1 = r0 + 64;
            float v0 = acc0[t][i] + bv;
            float v1 = acc1[t][i] + bv;
            if (act) { v0 = v0 > 0.f ? v0 : 0.01f * v0; v1 = v1 > 0.f ? v1 : 0.01f * v1; }
            if (r0 < M) {
                if (C)  C[(size_t)r0 * HID_ + col] = v0;
                if (Cb) *reinterpret_cast<unsigned short*>(&Cb[(size_t)r0 * HID_ + col]) = f2bf(v0);
            }
            if (r1 < M) {
                if (C)  C[(size_t)r1 * HID_ + col] = v1;
                if (Cb) *reinterpret_cast<unsigned short*>(&Cb[(size_t)r1 * HID_ + col]) = f2bf(v1);
            }
            if (gu >= 0) {
                if (r0 < M) psum[t] += v0;
                if (r1 < M) psum[t] += v1;
            } else if (gu == -1) {
                if (r0 < M) atomicAdd(&pooled[batch_p[r0] * HID_ + col], v0);
                if (r1 < M) atomicAdd(&pooled[batch_p[r1] * HID_ + col], v1);
            }
        }
    }
    if (gu >= 0) {
#pragma unroll
        for (int t = 0; t < 10; t++) {
            psum[t] += __shfl_xor(psum[t], 16);
            psum[t] += __shfl_xor(psum[t], 32);
        }
        if (q == 0) {
#pragma unroll
            for (int t = 0; t < 10; t++)
                atomicAdd(&pooled[gu * HID_ + t * 16 + fr], psum[t]);
        }
    }
}

// ---------- fused edge softmax + aggregation + bias + leaky + LayerNorm ----------
// One wave per destination node. Channel map: lane l owns ch {2l,2l+1}; lanes 0..15
// additionally own {128+2l,128+2l+1} (head 4). 4B ushort2 gathers (2 loads/edge).
__global__ __launch_bounds__(256) void k_att_agg(const int* __restrict__ rowptr,
                                                 const int2* __restrict__ epair,
                                                 const float* __restrict__ als, const float* __restrict__ ald,
                                                 const __hip_bfloat16* __restrict__ hmat,
                                                 float* __restrict__ alphap,      // [ET_*5] overflow scratch
                                                 float* __restrict__ alpha_out,   // [ET_*5] edge-id order
                                                 const float* __restrict__ bias,
                                                 const float* __restrict__ lns, const float* __restrict__ lnb,
                                                 __hip_bfloat16* __restrict__ outb) {
    __shared__ float sExp[4][64 * 5];
    __shared__ int2  sPair[4][64];
    int wv   = threadIdx.x >> 6;
    int lane = threadIdx.x & 63;
    int node = blockIdx.x * 4 + wv;
    if (node >= NN) return;
    int start = rowptr[node], end = rowptr[node + 1];
    int deg = end - start;
    bool fits = (deg <= 64);
    float ad[5];
#pragma unroll
    for (int h = 0; h < 5; h++) ad[h] = ald[node * 5 + h];

    // ---- pass 1: exp(leaky(logit)), lane-parallel over edges ----
    float sm[5] = {0.f, 0.f, 0.f, 0.f, 0.f};
    for (int j = start + lane; j < end; j += 64) {
        int2 p = epair[j];
        const float* as = &als[(size_t)p.y * 5];
        int idx = j - start;
        if (fits) sPair[wv][idx] = p;
#pragma unroll
        for (int h = 0; h < 5; h++) {
            float l = as[h] + ad[h];
            l = l > 0.f ? l : 0.2f * l;
            float ex = __expf(fminf(l, 60.f));
            sm[h] += ex;
            if (fits) sExp[wv][idx * 5 + h] = ex;
            else      alphap[(size_t)j * 5 + h] = ex;
        }
    }
#pragma unroll
    for (int off = 32; off >= 1; off >>= 1)
#pragma unroll
        for (int h = 0; h < 5; h++) sm[h] += __shfl_xor(sm[h], off);
    float inv[5];
#pragma unroll
    for (int h = 0; h < 5; h++) inv[h] = 1.f / (sm[h] + 1e-16f);

    int h0 = lane >> 4;            // head of ch pair (2l,2l+1): 0..3
    bool lo16 = lane < 16;         // lanes 0..15 own head-4 pair {128+2l,128+2l+1}
    int c01 = 2 * lane;            // first ch pair
    int c2  = 128 + 2 * lane;      // second ch pair (lo16 only; 128..158)
    float2 A  = make_float2(0.f, 0.f), B2 = make_float2(0.f, 0.f);
    float2 A2 = make_float2(0.f, 0.f), B22 = make_float2(0.f, 0.f);

    if (fits) {
        // ---- scatter normalized alpha (lane-parallel) ----
        if (lane < deg) {
            int2 p = sPair[wv][lane];
            float* ao = &alpha_out[(size_t)p.x * 5];
#pragma unroll
            for (int h = 0; h < 5; h++) ao[h] = sExp[wv][lane * 5 + h] * inv[h];
        }
        // ---- aggregation: serial over edges, ch pairs across lanes ----
        int idx = 0;
        for (; idx + 1 < deg; idx += 2) {
            int sA = sPair[wv][idx].y, sB = sPair[wv][idx + 1].y;
            float wA = sExp[wv][idx * 5 + h0] * inv[h0];
            float wB = sExp[wv][(idx + 1) * 5 + h0] * inv[h0];
            const unsigned short* rA = (const unsigned short*)&hmat[(size_t)sA * HID_];
            const unsigned short* rB = (const unsigned short*)&hmat[(size_t)sB * HID_];
            float2 fA = bf2f2(*reinterpret_cast<const uint32_t*>(&rA[c01]));
            float2 fB = bf2f2(*reinterpret_cast<const uint32_t*>(&rB[c01]));
            A.x += wA * fA.x; A.y += wA * fA.y;
            B2.x += wB * fB.x; B2.y += wB * fB.y;
            if (lo16) {
                float wA4 = sExp[wv][idx * 5 + 4] * inv[4];
                float wB4 = sExp[wv][(idx + 1) * 5 + 4] * inv[4];
                float2 gA = bf2f2(*reinterpret_cast<const uint32_t*>(&rA[c2]));
                float2 gB = bf2f2(*reinterpret_cast<const uint32_t*>(&rB[c2]));
                A2.x += wA4 * gA.x; A2.y += wA4 * gA.y;
                B22.x += wB4 * gB.x; B22.y += wB4 * gB.y;
            }
        }
        if (idx < deg) {
            int sA = sPair[wv][idx].y;
            float wA = sExp[wv][idx * 5 + h0] * inv[h0];
            const unsigned short* rA = (const unsigned short*)&hmat[(size_t)sA * HID_];
            float2 fA = bf2f2(*reinterpret_cast<const uint32_t*>(&rA[c01]));
            A.x += wA * fA.x; A.y += wA * fA.y;
            if (lo16) {
                float wA4 = sExp[wv][idx * 5 + 4] * inv[4];
                float2 gA = bf2f2(*reinterpret_cast<const uint32_t*>(&rA[c2]));
                A2.x += wA4 * gA.x; A2.y += wA4 * gA.y;
            }
        }
    } else {
        // ---- overflow path (deg > 64): alpha staged in global scratch ----
        for (int j = start + lane; j < end; j += 64) {
            int2 p = epair[j];
            float* ao = &alpha_out[(size_t)p.x * 5];
#pragma unroll
            for (int h = 0; h < 5; h++) ao[h] = alphap[(size_t)j * 5 + h] * inv[h];
        }
        for (int j = start; j < end; j++) {
            int2 p = epair[j];
            const float* ap = &alphap[(size_t)j * 5];
            float wA = ap[h0] * inv[h0];
            const unsigned short* rA = (const unsigned short*)&hmat[(size_t)p.y * HID_];
            float2 fA = bf2f2(*reinterpret_cast<const uint32_t*>(&rA[c01]));
            A.x += wA * fA.x; A.y += wA * fA.y;
            if (lo16) {
                float wA4 = ap[4] * inv[4];
                float2 gA = bf2f2(*reinterpret_cast<const uint32_t*>(&rA[c2]));
                A2.x += wA4 * gA.x; A2.y += wA4 * gA.y;
            }
        }
    }
    A.x += B2.x; A.y += B2.y; A2.x += B22.x; A2.y += B22.y;

    // ---- bias + leaky(0.01) + LayerNorm ----
    float2 bb = *reinterpret_cast<const float2*>(&bias[c01]);
    float v0 = A.x + bb.x;  v0 = v0 > 0.f ? v0 : 0.01f * v0;
    float v1 = A.y + bb.y;  v1 = v1 > 0.f ? v1 : 0.01f * v1;
    float v2 = 0.f, v3 = 0.f;
    if (lo16) {
        float2 b2 = *reinterpret_cast<const float2*>(&bias[c2]);
        v2 = A2.x + b2.x; v2 = v2 > 0.f ? v2 : 0.01f * v2;
        v3 = A2.y + b2.y; v3 = v3 > 0.f ? v3 : 0.01f * v3;
    }
    float s  = v0 + v1 + v2 + v3;
    float sq = v0 * v0 + v1 * v1 + v2 * v2 + v3 * v3;
#pragma unroll
    for (int off = 32; off >= 1; off >>= 1) {
        s  += __shfl_xor(s, off);
        sq += __shfl_xor(sq, off);
    }
    float m = s * (1.f / 160.f);
    float r = rsqrtf(sq * (1.f / 160.f) - m * m + 1e-5f);
    size_t ob = (size_t)node * HID_;
    {
        float2 sc = *reinterpret_cast<const float2*>(&lns[c01]);
        float2 bi = *reinterpret_cast<const float2*>(&lnb[c01]);
        uint32_t pk = (uint32_t)f2bf((v0 - m) * r * sc.x + bi.x)
                    | ((uint32_t)f2bf((v1 - m) * r * sc.y + bi.y) << 16);
        *reinterpret_cast<uint32_t*>(&outb[ob + c01]) = pk;
    }
    if (lo16) {
        float2 sc = *reinterpret_cast<const float2*>(&lns[c2]);
        float2 bi = *reinterpret_cast<const float2*>(&lnb[c2]);
        uint32_t pk = (uint32_t)f2bf((v2 - m) * r * sc.x + bi.x)
                    | ((uint32_t)f2bf((v3 - m) * r * sc.y + bi.y) << 16);
        *reinterpret_cast<uint32_t*>(&outb[ob + c2]) = pk;
    }
}

// ---------------- readout MLP (single block) ----------------
__global__ __launch_bounds__(256) void k_mlp(const float* __restrict__ pooled, const int* __restrict__ batch,
                                             const float* __restrict__ W1, const float* __restrict__ b1,
                                             const float* __restrict__ lns, const float* __restrict__ lnb,
                                             const float* __restrict__ W2, const float* __restrict__ b2,
                                             float* __restrict__ rec) {
    __shared__ float P[GG][HID_];
    __shared__ float Z[GG][HID_];
    __shared__ float mu[GG], rr[GG], ic[GG];
    int t = threadIdx.x;
    if (t < GG) {
        int lo = lbound_i(batch, NN, t), hi = lbound_i(batch, NN, t + 1);
        ic[t] = 1.f / fmaxf((float)(hi - lo), 1.f);
    }
    __syncthreads();
    for (int i = t; i < GG * HID_; i += 256) P[i / HID_][i % HID_] = pooled[i] * ic[i / HID_];
    __syncthreads();
    for (int i = t; i < GG * HID_; i += 256) {
        int g = i / HID_, j = i % HID_;
        float acc = b1[j];
        for (int k = 0; k < HID_; k++) acc += P[g][k] * W1[k * HID_ + j];
        Z[g][j] = acc;
    }
    __syncthreads();
    if (t < GG) {
        float s = 0.f, sq = 0.f;
        for (int k = 0; k < HID_; k++) { float z = Z[t][k]; s += z; sq += z * z; }
        float m = s / (float)HID_;
        mu[t] = m;
        rr[t] = rsqrtf(sq / (float)HID_ - m * m + 1e-5f);
    }
    __syncthreads();
    for (int i = t; i < GG * HID_; i += 256) {
        int g = i / HID_, j = i % HID_;
        float z = (Z[g][j] - mu[g]) * rr[g] * lns[j] + lnb[j];
        Z[g][j] = fmaxf(z, 0.f);
    }
    __syncthreads();
    for (int i = t; i < GG * NC_; i += 256) {
        int g = i / NC_, j = i % NC_;
        float acc = b2[j];
        for (int k = 0; k < HID_; k++) acc += Z[g][k] * W2[k * NC_ + j];
        rec[g * NC_ + j] = acc;
    }
}

extern "C" void kernel_launch(void* const* d_in, const int* in_sizes, int n_in,
                              void* d_out, int out_size, void* d_ws, size_t ws_size,
                              hipStream_t stream) {
    const float* x    = (const float*)d_in[0];
    const int*   ei   = (const int*)d_in[1];
    const int*   batch= (const int*)d_in[2];
    const float* W1   = (const float*)d_in[3];
    const float* as1  = (const float*)d_in[4];
    const float* ad1  = (const float*)d_in[5];
    const float* b1   = (const float*)d_in[6];
    const float* ln1s = (const float*)d_in[7];
    const float* ln1b = (const float*)d_in[8];
    const float* W2   = (const float*)d_in[9];
    const float* as2  = (const float*)d_in[10];
    const float* ad2  = (const float*)d_in[11];
    const float* b2   = (const float*)d_in[12];
    const float* ln2s = (const float*)d_in[13];
    const float* ln2b = (const float*)d_in[14];
    const float* Wm   = (const float*)d_in[15];
    const float* bm   = (const float*)d_in[16];
    const float* Wm1  = (const float*)d_in[17];
    const float* bm1  = (const float*)d_in[18];
    const float* ln3s = (const float*)d_in[19];
    const float* ln3b = (const float*)d_in[20];
    const float* Wm2  = (const float*)d_in[21];
    const float* bm2  = (const float*)d_in[22];

    float* out    = (float*)d_out;
    float* xo     = out;                              // N*160
    float* rec    = out + (size_t)NN * HID_;          // 8*20
    float* alpha1 = rec + GG * NC_;                   // ET*5
    float* alpha2 = alpha1 + (size_t)ET_ * 5;         // ET*5

    char* w = (char*)d_ws;
    auto carve = [&](size_t bytes) { char* p = w; w += (bytes + 255) & ~(size_t)255; return p; };
    int*   deg    = (int*)carve((size_t)NN * 4);
    int*   rowptr = (int*)carve((size_t)(NN + 1) * 4);
    int*   cursor = (int*)carve((size_t)NN * 4);
    int2*  epair  = (int2*)carve((size_t)ET_ * 8);
    int*   bsum   = (int*)carve(64 * 4);
    __hip_bfloat16* hbuf  = (__hip_bfloat16*)carve((size_t)NN * HID_ * 2);
    __hip_bfloat16* xbufb = (__hip_bfloat16*)carve((size_t)NN * HID_ * 2);
    float* alphap = (float*)carve((size_t)ET_ * 5 * 4);
    float* als    = (float*)carve((size_t)NN * 5 * 4);
    float* ald    = (float*)carve((size_t)NN * 5 * 4);
    float* pooled = (float*)carve((size_t)GG * HID_ * 4);
    unsigned short* Wt1 = (unsigned short*)carve((size_t)HID_ * 512 * 2);
    unsigned short* Wt2 = (unsigned short*)carve((size_t)HID_ * HID_ * 2);
    unsigned short* Wmt = (unsigned short*)carve((size_t)HID_ * HID_ * 2);

    // ---- CSR by destination (rebuilt every call; ws is re-poisoned) ----
    hipMemsetAsync(deg, 0, (size_t)NN * 4, stream);
    k_hist<<<(ET_ + 255) / 256, 256, 0, stream>>>(ei, deg);
    int nb = (NN + 1023) / 1024;
    k_scan1<<<nb, 256, 0, stream>>>(deg, rowptr, bsum);
    k_scan2<<<1, 64, 0, stream>>>(bsum, nb);
    k_scan3<<<(NN + 1 + 255) / 256, 256, 0, stream>>>(rowptr, bsum, cursor);
    k_scatter<<<(ET_ + 255) / 256, 256, 0, stream>>>(ei, cursor, epair);

    // ---- weight prep (one launch) + pooled zero (needed before gemm3) ----
    const int PREP = HID_ * 512 + 2 * HID_ * HID_;
    k_prep_all<<<(PREP + 255) / 256, 256, 0, stream>>>(W1, Wt1, W2, Wt2, Wm, Wmt);
    hipMemsetAsync(pooled, 0, (size_t)GG * HID_ * 4, stream);

    const int NWB = (NN + 3) / 4;         // wave-per-node blocks (4 waves/block)
    const int GB  = (NN + 127) / 128;     // MFMA GEMM blocks

    // ---- layer 1 ----
    k_gemm_mfma<<<GB, 256, 0, stream>>>(x, Wt1, nullptr, hbuf, NN, FIN, 512, 0, nullptr, 0,
                                        as1, ad1, als, ald, nullptr, nullptr);
    k_att_agg<<<NWB, 256, 0, stream>>>(rowptr, epair, als, ald, hbuf, alphap, alpha1,
                                       b1, ln1s, ln1b, xbufb);

    // ---- layer 2 ----
    k_gemm_mfma<<<GB, 256, 0, stream>>>(xbufb, Wt2, nullptr, hbuf, NN, HID_, HID_, 1, nullptr, 0,
                                        as2, ad2, als, ald, nullptr, nullptr);
    k_att_agg<<<NWB, 256, 0, stream>>>(rowptr, epair, als, ald, hbuf, alphap, alpha2,
                                       b2, ln2s, ln2b, xbufb);

    // ---- readout: GEMM + fused mean-pool partials ----
    k_gemm_mfma<<<GB, 256, 0, stream>>>(xbufb, Wmt, xo, nullptr, NN, HID_, HID_, 1, bm, 1,
                                        nullptr, nullptr, nullptr, nullptr, batch, pooled);
    k_mlp<<<1, 256, 0, stream>>>(pooled, batch, Wm1, bm1, ln3s, ln3b, Wm2, bm2, rec);
}